// Round 11
// baseline (1563.960 us; speedup 1.0000x reference)
//
#include <hip/hip_runtime.h>
#include <hip/hip_bf16.h>

// GeometryAwareCrossAttention — round 11:
//  ffn_mfma_k: fit 3 WG/CU without spill. Cross-round forensics: occupancy
//  pinned at 45% (2 WG) in r7/r9/r10 because TOTAL unified regfile use =
//  VGPR(64) + AGPR accumulators(48) = 112 -> 4 waves/SIMD. For 6 waves/SIMD
//  (3 WG) total must be <=85:
//   * LDS -> exactly 48KB (f1q [64][128] XOR-swizzled, r8-verified).
//   * phase B split into 2 row-halves: transient accB 16 -> 8 regs.
//   * __launch_bounds__(512,6).
//  Barrier placement unchanged (r7-verified 2/quarter).
//  Everything else = r10 verbatim.

typedef __hip_bfloat16 bf16;
typedef __attribute__((ext_vector_type(8))) short bf16x8;
typedef __attribute__((ext_vector_type(4))) float f32x4;

__device__ __forceinline__ float b2f(bf16 v) { return __bfloat162float(v); }
__device__ __forceinline__ float us2f(unsigned short u) {
  union { unsigned int v; float f; } c; c.v = ((unsigned int)u) << 16; return c.f;
}
__device__ __forceinline__ unsigned short f2bu(float x) {
  bf16 t = __float2bfloat16(x);
  unsigned short u; __builtin_memcpy(&u, &t, 2); return u;
}
__device__ __forceinline__ float4 ld4(const float* p) {
  return *reinterpret_cast<const float4*>(p);
}
__device__ __forceinline__ float4 ldnt4(const float* p) {
  f32x4 v = __builtin_nontemporal_load(reinterpret_cast<const f32x4*>(p));
  return make_float4(v.x, v.y, v.z, v.w);
}
__device__ __forceinline__ float wsum(float v) {
#pragma unroll
  for (int o = 32; o > 0; o >>= 1) v += __shfl_xor(v, o, 64);
  return v;
}
// swizzled LDS fragment read: 8 contiguous bf16 at (row, k), XOR-swizzled.
__device__ __forceinline__ bf16x8 lds_frag(const unsigned short* base, int stride,
                                           int row, int k) {
  return *reinterpret_cast<const bf16x8*>(base + row * stride +
                                          (k ^ ((row & 7) << 3)));
}

// ---------------- segment boundaries (block_id is sorted) ----------------
__global__ void bounds_k(const int* __restrict__ seg, int* __restrict__ bs,
                         int* __restrict__ be, int N) {
  int i = blockIdx.x * 256 + threadIdx.x;
  if (i >= N) return;
  int b = seg[i];
  if (i == 0 || seg[i - 1] != b) bs[b] = i;
  if (i == N - 1 || seg[i + 1] != b) be[b] = i + 1;
}

// ---------------- per-block centroid ----------------
__global__ void cent_k(const float* __restrict__ pos, const int* __restrict__ bs,
                       const int* __restrict__ be, float* __restrict__ cent, int NB) {
  int b = blockIdx.x * 256 + threadIdx.x;
  if (b >= NB) return;
  int s0 = bs[b], s1 = be[b];
  float sx = 0.f, sy = 0.f, sz = 0.f;
  for (int i = s0; i < s1; ++i) {
    sx += pos[(size_t)i * 3 + 0];
    sy += pos[(size_t)i * 3 + 1];
    sz += pos[(size_t)i * 3 + 2];
  }
  float inv = 1.f / fmaxf((float)(s1 - s0), 1.f);
  cent[(size_t)b * 3 + 0] = sx * inv;
  cent[(size_t)b * 3 + 1] = sy * inv;
  cent[(size_t)b * 3 + 2] = sz * inv;
}

// ---------------- per-atom RBF -> geom [N,64] (bf16 scratch) --------------
__global__ __launch_bounds__(256) void geom_k(
    const float* __restrict__ pos, const int* __restrict__ seg,
    const float* __restrict__ cent, const float* __restrict__ centers,
    const float* __restrict__ widths, const float* __restrict__ Wg,
    const float* __restrict__ bg, bf16* __restrict__ geom, int N) {
  __shared__ float sWg[16][64];
  __shared__ float sc[16], sw[16], sbg[64];
  int t = threadIdx.x;
  if (t < 16) {
    sc[t] = centers[t];
    float w = widths[t];
    sw[t] = 1.f / (2.f * w * w);
  }
  for (int j = t; j < 1024; j += 256) sWg[j >> 6][j & 63] = Wg[j];
  if (t < 64) sbg[t] = bg[t];
  __syncthreads();
  int i = blockIdx.x * 256 + t;
  if (i >= N) return;
  int b = seg[i];
  float dx = pos[(size_t)i * 3 + 0] - cent[(size_t)b * 3 + 0];
  float dy = pos[(size_t)i * 3 + 1] - cent[(size_t)b * 3 + 1];
  float dz = pos[(size_t)i * 3 + 2] - cent[(size_t)b * 3 + 2];
  float d = sqrtf(dx * dx + dy * dy + dz * dz);
  float r[16];
#pragma unroll
  for (int j = 0; j < 16; ++j) {
    float dd = d - sc[j];
    r[j] = expf(-dd * dd * sw[j]);
  }
  bf16* gp = geom + (size_t)i * 64;
  for (int g0 = 0; g0 < 64; g0 += 4) {
    float a0 = sbg[g0], a1 = sbg[g0 + 1], a2 = sbg[g0 + 2], a3 = sbg[g0 + 3];
#pragma unroll
    for (int j = 0; j < 16; ++j) {
      float rj = r[j];
      a0 += rj * sWg[j][g0];
      a1 += rj * sWg[j][g0 + 1];
      a2 += rj * sWg[j][g0 + 2];
      a3 += rj * sWg[j][g0 + 3];
    }
    ushort4 o;
    o.x = f2bu(a0); o.y = f2bu(a1); o.z = f2bu(a2); o.w = f2bu(a3);
    *reinterpret_cast<ushort4*>(gp + g0) = o;
  }
}

// ---------------- weight transpose+cast: out[n*K+k] = bf16(in[k*N+n]) -----
__global__ void tr_k(const float* __restrict__ in, unsigned short* __restrict__ out,
                     int K, int N) {
  int idx = blockIdx.x * 256 + threadIdx.x;
  if (idx >= N * K) return;
  int n = idx / K, k = idx % K;
  out[idx] = f2bu(in[(size_t)k * N + n]);
}
// plain cast
__global__ void cast_k(const float* __restrict__ in, unsigned short* __restrict__ out,
                       int n) {
  int idx = blockIdx.x * 256 + threadIdx.x;
  if (idx < n) out[idx] = f2bu(in[idx]);
}

// ---- MFMA-fragment packing for FFN weights (r7 16x16 layout) ----
__global__ void pack1_k(const float* __restrict__ Wf1,
                        unsigned short* __restrict__ P) {
  int idx = blockIdx.x * 256 + threadIdx.x;
  if (idx >= 512 * 256) return;
  int e = idx & 7;
  int l = (idx >> 3) & 63;
  int blk = idx >> 9;
  int ks = blk & 7, wv = (blk >> 3) & 7, q = blk >> 6;
  int n = q * 128 + wv * 16 + (l & 15);
  int k = ks * 32 + (l >> 4) * 8 + e;
  P[idx] = f2bu(Wf1[(size_t)k * 512 + n]);
}
__global__ void pack2_k(const float* __restrict__ Wf2,
                        unsigned short* __restrict__ P) {
  int idx = blockIdx.x * 256 + threadIdx.x;
  if (idx >= 512 * 256) return;
  int e = idx & 7;
  int l = (idx >> 3) & 63;
  int blk = idx >> 9;
  int ks = blk & 3, q = (blk >> 2) & 3, nt = (blk >> 4) & 1, wv = blk >> 5;
  int n = wv * 32 + nt * 16 + (l & 15);
  int k = q * 128 + ks * 32 + (l >> 4) * 8 + e;
  P[idx] = f2bu(Wf2[(size_t)k * 256 + n]);
}

// ---------------- blk1: Q = bfeat@WqT+bq (LDS only); u = Q@Wk^T; cb = Q.bk -
__global__ __launch_bounds__(512, 4) void blk1_k(
    const float* __restrict__ bfeat, const unsigned short* __restrict__ WqT,
    const float* __restrict__ bq, const unsigned short* __restrict__ WkC,
    const float* __restrict__ bk, float* __restrict__ u, float* __restrict__ cb,
    int NB) {
  __shared__ unsigned short x_lds[64 * 256];  // 32 KiB
  __shared__ unsigned short q_lds[64 * 256];  // 32 KiB
  const int t = threadIdx.x;
  const int lane = t & 63, wv = t >> 6, l15 = lane & 15, lhi = lane >> 4;
  const int r0 = blockIdx.x * 64;
  for (int rr = 0; rr < 8; ++rr) {
    int r = wv * 8 + rr;
    int row = r0 + r; if (row >= NB) row = NB - 1;
    float4 v = ldnt4(bfeat + (size_t)row * 256 + lane * 4);
    ushort4 o; o.x = f2bu(v.x); o.y = f2bu(v.y); o.z = f2bu(v.z); o.w = f2bu(v.w);
    *reinterpret_cast<ushort4*>(&x_lds[r * 256 + ((lane * 4) ^ ((r & 7) << 3))]) = o;
  }
  __syncthreads();
  {
    f32x4 acc[2][4];
#pragma unroll
    for (int nt = 0; nt < 2; ++nt)
#pragma unroll
      for (int rt = 0; rt < 4; ++rt) acc[nt][rt] = (f32x4){0.f, 0.f, 0.f, 0.f};
#pragma unroll
    for (int ks = 0; ks < 8; ++ks) {
      bf16x8 a[4];
#pragma unroll
      for (int rt = 0; rt < 4; ++rt)
        a[rt] = lds_frag(x_lds, 256, rt * 16 + l15, ks * 32 + lhi * 8);
#pragma unroll
      for (int nt = 0; nt < 2; ++nt) {
        bf16x8 b = *reinterpret_cast<const bf16x8*>(
            WqT + (size_t)(wv * 32 + nt * 16 + l15) * 256 + ks * 32 + lhi * 8);
#pragma unroll
        for (int rt = 0; rt < 4; ++rt)
          acc[nt][rt] = __builtin_amdgcn_mfma_f32_16x16x32_bf16(a[rt], b, acc[nt][rt], 0, 0, 0);
      }
    }
#pragma unroll
    for (int nt = 0; nt < 2; ++nt) {
      int col = wv * 32 + nt * 16 + l15;
      float bb = bq[col];
#pragma unroll
      for (int rt = 0; rt < 4; ++rt)
#pragma unroll
        for (int j = 0; j < 4; ++j) {
          int row = rt * 16 + lhi * 4 + j;
          q_lds[row * 256 + (col ^ ((row & 7) << 3))] = f2bu(acc[nt][rt][j] + bb);
        }
    }
  }
  __syncthreads();
  if (t < 64) {
    float a = 0.f;
    for (int c = 0; c < 256; ++c)
      a += us2f(q_lds[t * 256 + (c ^ ((t & 7) << 3))]) * bk[c];
    int row = r0 + t;
    if (row < NB) cb[row] = a;
  }
  for (int j = 0; j < 3; ++j) {
    int tile = wv + 8 * j;
    if (tile >= 20) break;
    f32x4 acc[4];
#pragma unroll
    for (int rt = 0; rt < 4; ++rt) acc[rt] = (f32x4){0.f, 0.f, 0.f, 0.f};
#pragma unroll
    for (int ks = 0; ks < 8; ++ks) {
      bf16x8 b = *reinterpret_cast<const bf16x8*>(
          WkC + (size_t)(tile * 16 + l15) * 256 + ks * 32 + lhi * 8);
#pragma unroll
      for (int rt = 0; rt < 4; ++rt) {
        bf16x8 a = lds_frag(q_lds, 256, rt * 16 + l15, ks * 32 + lhi * 8);
        acc[rt] = __builtin_amdgcn_mfma_f32_16x16x32_bf16(a, b, acc[rt], 0, 0, 0);
      }
    }
    int n = tile * 16 + l15;
#pragma unroll
    for (int rt = 0; rt < 4; ++rt)
#pragma unroll
      for (int jj = 0; jj < 4; ++jj) {
        int row = r0 + rt * 16 + lhi * 4 + jj;
        if (row < NB) u[(size_t)row * 320 + n] = acc[rt][jj];
      }
  }
}

// ---------------- segment attention: branchless softmax (no max) ----------
__global__ __launch_bounds__(256) void attn_k(
    const float* __restrict__ feat, const bf16* __restrict__ geom,
    const float* __restrict__ u, const float* __restrict__ cbArr,
    const int* __restrict__ bs, const int* __restrict__ be,
    float* __restrict__ S, int NB) {
  int wave = threadIdx.x >> 6;
  int lane = threadIdx.x & 63;
  int b = blockIdx.x * 4 + wave;
  if (b >= NB) return;
  int s0 = bs[b], s1 = be[b];
  if (s1 <= s0) return;  // empty block: S row never consumed downstream
  const float* ub = u + (size_t)b * 320;
  float4 uv = ld4(ub + lane * 4);
  float ug = ub[256 + lane];
  float cb = cbArr[b];
  const float scale = 0.0625f;  // 1/sqrt(256)
  float l = 0.f;
  float a0 = 0.f, a1 = 0.f, a2 = 0.f, a3 = 0.f, ag = 0.f;
  for (int i = s0; i < s1; ++i) {
    float4 f = ldnt4(feat + (size_t)i * 256 + lane * 4);
    float gm = b2f(geom[(size_t)i * 64 + lane]);
    float p = f.x * uv.x + f.y * uv.y + f.z * uv.z + f.w * uv.w + gm * ug;
    p = wsum(p);
    float e = __expf((p + cb) * scale);  // wave-uniform
    l += e;
    a0 += e * f.x; a1 += e * f.y; a2 += e * f.z; a3 += e * f.w;
    ag += e * gm;
  }
  float inv = 1.f / l;
  float* Sb = S + (size_t)b * 320;
  Sb[lane * 4 + 0] = a0 * inv; Sb[lane * 4 + 1] = a1 * inv;
  Sb[lane * 4 + 2] = a2 * inv; Sb[lane * 4 + 3] = a3 * inv;
  Sb[256 + lane] = ag * inv;
}

// ---------------- blk2: ctx = S@Wv+bv; t1 = relu(ctx@Wc1+bc1); upd = t1@Wc2+bc2
__global__ __launch_bounds__(512, 4) void blk2_k(
    const float* __restrict__ S, const unsigned short* __restrict__ WvT,
    const float* __restrict__ bv, const unsigned short* __restrict__ Wc1T,
    const float* __restrict__ bc1, const unsigned short* __restrict__ Wc2T,
    const float* __restrict__ bc2, float* __restrict__ upd, int NB) {
  __shared__ unsigned short s_lds[64 * 320];  // 40 KiB
  const int t = threadIdx.x;
  const int lane = t & 63, wv = t >> 6, l15 = lane & 15, lhi = lane >> 4;
  const int r0 = blockIdx.x * 64;
  for (int rr = 0; rr < 8; ++rr) {
    int r = wv * 8 + rr;
    int row = r0 + r; if (row >= NB) row = NB - 1;
    float4 v = ld4(S + (size_t)row * 320 + lane * 4);
    ushort4 o; o.x = f2bu(v.x); o.y = f2bu(v.y); o.z = f2bu(v.z); o.w = f2bu(v.w);
    *reinterpret_cast<ushort4*>(&s_lds[r * 320 + ((lane * 4) ^ ((r & 7) << 3))]) = o;
    float g = S[(size_t)row * 320 + 256 + lane];
    s_lds[r * 320 + ((256 + lane) ^ ((r & 7) << 3))] = f2bu(g);
  }
  __syncthreads();
  f32x4 acc[2][4];
#pragma unroll
  for (int nt = 0; nt < 2; ++nt)
#pragma unroll
    for (int rt = 0; rt < 4; ++rt) acc[nt][rt] = (f32x4){0.f, 0.f, 0.f, 0.f};
#pragma unroll
  for (int ks = 0; ks < 10; ++ks) {
    bf16x8 a[4];
#pragma unroll
    for (int rt = 0; rt < 4; ++rt)
      a[rt] = lds_frag(s_lds, 320, rt * 16 + l15, ks * 32 + lhi * 8);
#pragma unroll
    for (int nt = 0; nt < 2; ++nt) {
      bf16x8 b = *reinterpret_cast<const bf16x8*>(
          WvT + (size_t)(wv * 32 + nt * 16 + l15) * 320 + ks * 32 + lhi * 8);
#pragma unroll
      for (int rt = 0; rt < 4; ++rt)
        acc[nt][rt] = __builtin_amdgcn_mfma_f32_16x16x32_bf16(a[rt], b, acc[nt][rt], 0, 0, 0);
    }
  }
  __syncthreads();
#pragma unroll
  for (int nt = 0; nt < 2; ++nt) {
    int col = wv * 32 + nt * 16 + l15;
    float bb = bv[col];
#pragma unroll
    for (int rt = 0; rt < 4; ++rt)
#pragma unroll
      for (int j = 0; j < 4; ++j) {
        int row = rt * 16 + lhi * 4 + j;
        s_lds[row * 256 + (col ^ ((row & 7) << 3))] = f2bu(acc[nt][rt][j] + bb);
      }
  }
  __syncthreads();
#pragma unroll
  for (int nt = 0; nt < 2; ++nt)
#pragma unroll
    for (int rt = 0; rt < 4; ++rt) acc[nt][rt] = (f32x4){0.f, 0.f, 0.f, 0.f};
#pragma unroll
  for (int ks = 0; ks < 8; ++ks) {
    bf16x8 a[4];
#pragma unroll
    for (int rt = 0; rt < 4; ++rt)
      a[rt] = lds_frag(s_lds, 256, rt * 16 + l15, ks * 32 + lhi * 8);
#pragma unroll
    for (int nt = 0; nt < 2; ++nt) {
      bf16x8 b = *reinterpret_cast<const bf16x8*>(
          Wc1T + (size_t)(wv * 32 + nt * 16 + l15) * 256 + ks * 32 + lhi * 8);
#pragma unroll
      for (int rt = 0; rt < 4; ++rt)
        acc[nt][rt] = __builtin_amdgcn_mfma_f32_16x16x32_bf16(a[rt], b, acc[nt][rt], 0, 0, 0);
    }
  }
  __syncthreads();
#pragma unroll
  for (int nt = 0; nt < 2; ++nt) {
    int col = wv * 32 + nt * 16 + l15;
    float bb = bc1[col];
#pragma unroll
    for (int rt = 0; rt < 4; ++rt)
#pragma unroll
      for (int j = 0; j < 4; ++j) {
        int row = rt * 16 + lhi * 4 + j;
        s_lds[row * 256 + (col ^ ((row & 7) << 3))] = f2bu(fmaxf(acc[nt][rt][j] + bb, 0.f));
      }
  }
  __syncthreads();
#pragma unroll
  for (int nt = 0; nt < 2; ++nt)
#pragma unroll
    for (int rt = 0; rt < 4; ++rt) acc[nt][rt] = (f32x4){0.f, 0.f, 0.f, 0.f};
#pragma unroll
  for (int ks = 0; ks < 8; ++ks) {
    bf16x8 a[4];
#pragma unroll
    for (int rt = 0; rt < 4; ++rt)
      a[rt] = lds_frag(s_lds, 256, rt * 16 + l15, ks * 32 + lhi * 8);
#pragma unroll
    for (int nt = 0; nt < 2; ++nt) {
      bf16x8 b = *reinterpret_cast<const bf16x8*>(
          Wc2T + (size_t)(wv * 32 + nt * 16 + l15) * 256 + ks * 32 + lhi * 8);
#pragma unroll
      for (int rt = 0; rt < 4; ++rt)
        acc[nt][rt] = __builtin_amdgcn_mfma_f32_16x16x32_bf16(a[rt], b, acc[nt][rt], 0, 0, 0);
    }
  }
#pragma unroll
  for (int nt = 0; nt < 2; ++nt) {
    int col = wv * 32 + nt * 16 + l15;
    float bb = bc2[col];
#pragma unroll
    for (int rt = 0; rt < 4; ++rt)
#pragma unroll
      for (int j = 0; j < 4; ++j) {
        int row = r0 + rt * 16 + lhi * 4 + j;
        if (row < NB) upd[(size_t)row * 256 + col] = acc[nt][rt][j] + bb;
      }
  }
}

// ---------------- fused LN1 -> FFN(MFMA, quarter-split) -> LN2 ------------
// 512 thr = 8 waves; LDS: h[64][256] 32K + f1q[64][128] 16K = 48KB exactly.
// Phase B in 2 row-halves (transient accB = 8 regs); total acc = 40.
// __launch_bounds__(512,6): reg budget 85 -> 6 waves/SIMD -> 3 WG/CU.
__global__ __launch_bounds__(512, 6) void ffn_mfma_k(
    const float* __restrict__ feat, const int* __restrict__ seg,
    const float* __restrict__ upd, const unsigned short* __restrict__ Wf1P,
    const float* __restrict__ bf1_, const unsigned short* __restrict__ Wf2P,
    const float* __restrict__ bf2_, const float* __restrict__ lng1,
    const float* __restrict__ lnb1, const float* __restrict__ lng2,
    const float* __restrict__ lnb2, float* __restrict__ out, int N) {
  __shared__ unsigned short h_lds[64 * 256];   // 32K; later y = h + ffn2
  __shared__ unsigned short f1q_lds[64 * 128]; // 16K, XOR-swizzled
  const int t = threadIdx.x;
  const int lane = t & 63;
  const int wv = t >> 6;
  const int l15 = lane & 15;
  const int lhi = lane >> 4;
  const int r0 = blockIdx.x * 64;

  // ---- phase A: h = LN1(feat + upd[seg]) -> bf16 swizzled LDS ----
  {
    float4 g1v = ld4(lng1 + lane * 4);
    float4 b1v = ld4(lnb1 + lane * 4);
    for (int rr = 0; rr < 8; ++rr) {
      int r = wv * 8 + rr;
      int row = r0 + r;
      if (row >= N) row = N - 1;
      int bidx = seg[row];
      float4 xf = ldnt4(feat + (size_t)row * 256 + lane * 4);
      float4 up = ld4(upd + (size_t)bidx * 256 + lane * 4);
      float x0 = xf.x + up.x, x1 = xf.y + up.y;
      float x2 = xf.z + up.z, x3 = xf.w + up.w;
      float s = wsum(x0 + x1 + x2 + x3);
      float s2 = wsum(x0 * x0 + x1 * x1 + x2 * x2 + x3 * x3);
      float mean = s * (1.f / 256.f);
      float var = s2 * (1.f / 256.f) - mean * mean;
      float rstd = rsqrtf(var + 1e-5f);
      ushort4 o;
      o.x = f2bu((x0 - mean) * rstd * g1v.x + b1v.x);
      o.y = f2bu((x1 - mean) * rstd * g1v.y + b1v.y);
      o.z = f2bu((x2 - mean) * rstd * g1v.z + b1v.z);
      o.w = f2bu((x3 - mean) * rstd * g1v.w + b1v.w);
      *reinterpret_cast<ushort4*>(&h_lds[r * 256 + ((lane * 4) ^ ((r & 7) << 3))]) = o;
    }
  }
  __syncthreads();

  f32x4 accC[2][4];
#pragma unroll
  for (int nt = 0; nt < 2; ++nt)
#pragma unroll
    for (int rt = 0; rt < 4; ++rt) accC[nt][rt] = (f32x4){0.f, 0.f, 0.f, 0.f};

#pragma unroll 1
  for (int q = 0; q < 4; ++q) {
    // ---- phase B: f1 quarter (128 cols); wave owns 16 cols; 2 row-halves --
#pragma unroll 1
    for (int rh = 0; rh < 2; ++rh) {
      f32x4 accB[2];
      accB[0] = (f32x4){0.f, 0.f, 0.f, 0.f};
      accB[1] = (f32x4){0.f, 0.f, 0.f, 0.f};
      const unsigned short* wb =
          Wf1P + (size_t)((q * 8 + wv) * 8) * 512 + lane * 8;
      bf16x8 bcur = *reinterpret_cast<const bf16x8*>(wb);
#pragma unroll
      for (int ks = 0; ks < 8; ++ks) {
        bf16x8 bnx = bcur;
        if (ks < 7) bnx = *reinterpret_cast<const bf16x8*>(wb + (ks + 1) * 512);
        int k = ks * 32 + lhi * 8;
        bf16x8 a0 = lds_frag(h_lds, 256, (rh * 2 + 0) * 16 + l15, k);
        bf16x8 a1 = lds_frag(h_lds, 256, (rh * 2 + 1) * 16 + l15, k);
        accB[0] = __builtin_amdgcn_mfma_f32_16x16x32_bf16(a0, bcur, accB[0], 0, 0, 0);
        accB[1] = __builtin_amdgcn_mfma_f32_16x16x32_bf16(a1, bcur, accB[1], 0, 0, 0);
        bcur = bnx;
      }
      int coll = wv * 16 + l15;
      float bb = bf1_[q * 128 + coll];
#pragma unroll
      for (int rt = 0; rt < 2; ++rt)
#pragma unroll
        for (int j = 0; j < 4; ++j) {
          int row = (rh * 2 + rt) * 16 + lhi * 4 + j;
          f1q_lds[row * 128 + (coll ^ ((row & 7) << 3))] =
              f2bu(fmaxf(accB[rt][j] + bb, 0.f));
        }
    }
    __syncthreads();  // f1q writes visible; prev quarter's C-reads done
    // ---- phase C: accC += f1q @ Wf2T[:, q*128:+128] (packed P2) ----
#pragma unroll
    for (int ks = 0; ks < 4; ++ks) {
      int k = ks * 32 + lhi * 8;
      bf16x8 a0 = lds_frag(f1q_lds, 128, 0 * 16 + l15, k);
      bf16x8 a1 = lds_frag(f1q_lds, 128, 1 * 16 + l15, k);
      bf16x8 a2 = lds_frag(f1q_lds, 128, 2 * 16 + l15, k);
      bf16x8 a3 = lds_frag(f1q_lds, 128, 3 * 16 + l15, k);
#pragma unroll
      for (int nt = 0; nt < 2; ++nt) {
        bf16x8 b = *reinterpret_cast<const bf16x8*>(
            Wf2P + (size_t)((wv * 2 + nt) * 16 + q * 4 + ks) * 512 + lane * 8);
        accC[nt][0] = __builtin_amdgcn_mfma_f32_16x16x32_bf16(a0, b, accC[nt][0], 0, 0, 0);
        accC[nt][1] = __builtin_amdgcn_mfma_f32_16x16x32_bf16(a1, b, accC[nt][1], 0, 0, 0);
        accC[nt][2] = __builtin_amdgcn_mfma_f32_16x16x32_bf16(a2, b, accC[nt][2], 0, 0, 0);
        accC[nt][3] = __builtin_amdgcn_mfma_f32_16x16x32_bf16(a3, b, accC[nt][3], 0, 0, 0);
      }
    }
    __syncthreads();
  }

  // ---- y = h + ffn2 + bf2, in place in h_lds ----
#pragma unroll
  for (int nt = 0; nt < 2; ++nt) {
    int c = wv * 32 + nt * 16 + l15;
    float bb = bf2_[c];
#pragma unroll
    for (int rt = 0; rt < 4; ++rt)
#pragma unroll
      for (int j = 0; j < 4; ++j) {
        int row = rt * 16 + lhi * 4 + j;
        int idx = row * 256 + (c ^ ((row & 7) << 3));
        h_lds[idx] = f2bu(us2f(h_lds[idx]) + accC[nt][rt][j] + bb);
      }
  }
  __syncthreads();

  // ---- LN2(y) -> out (plain cached store) ----
  {
    float4 g2v = ld4(lng2 + lane * 4);
    float4 b2v = ld4(lnb2 + lane * 4);
    for (int rr = 0; rr < 8; ++rr) {
      int r = wv * 8 + rr;
      int row = r0 + r;
      if (row >= N) row = N - 1;
      int idx = r * 256 + ((lane * 4) ^ ((r & 7) << 3));
      ushort4 yv = *reinterpret_cast<const ushort4*>(&h_lds[idx]);
      float y0 = us2f(yv.x), y1 = us2f(yv.y), y2 = us2f(yv.z), y3 = us2f(yv.w);
      float s = wsum(y0 + y1 + y2 + y3);
      float s2 = wsum(y0 * y0 + y1 * y1 + y2 * y2 + y3 * y3);
      float mean = s * (1.f / 256.f);
      float var = s2 * (1.f / 256.f) - mean * mean;
      float rstd = rsqrtf(var + 1e-5f);
      float4 o;
      o.x = (y0 - mean) * rstd * g2v.x + b2v.x;
      o.y = (y1 - mean) * rstd * g2v.y + b2v.y;
      o.z = (y2 - mean) * rstd * g2v.z + b2v.z;
      o.w = (y3 - mean) * rstd * g2v.w + b2v.w;
      *reinterpret_cast<float4*>(out + (size_t)row * 256 + lane * 4) = o;
    }
  }
}

extern "C" void kernel_launch(void* const* d_in, const int* in_sizes, int n_in,
                              void* d_out, int out_size, void* d_ws, size_t ws_size,
                              hipStream_t stream) {
  const float* feat = (const float*)d_in[0];
  const float* pos = (const float*)d_in[1];
  const float* bfeat = (const float*)d_in[2];
  const int* seg = (const int*)d_in[3];
  const float* centers = (const float*)d_in[4];
  const float* widths = (const float*)d_in[5];
  const float* Wg = (const float*)d_in[6];
  const float* bg = (const float*)d_in[7];
  const float* Wq = (const float*)d_in[8];
  const float* bq = (const float*)d_in[9];
  const float* Wk = (const float*)d_in[10];
  const float* bk = (const float*)d_in[11];
  const float* Wv = (const float*)d_in[12];
  const float* bv = (const float*)d_in[13];
  const float* Wc1 = (const float*)d_in[14];
  const float* bc1 = (const float*)d_in[15];
  const float* Wc2 = (const float*)d_in[16];
  const float* bc2 = (const float*)d_in[17];
  const float* Wf1 = (const float*)d_in[18];
  const float* bf1_ = (const float*)d_in[19];
  const float* Wf2 = (const float*)d_in[20];
  const float* bf2_ = (const float*)d_in[21];
  const float* lng1 = (const float*)d_in[22];
  const float* lnb1 = (const float*)d_in[23];
  const float* lng2 = (const float*)d_in[24];
  const float* lnb2 = (const float*)d_in[25];
  float* out = (float*)d_out;

  const int N = in_sizes[0] / 256;   // 500000
  const int NB = in_sizes[2] / 256;  // 50000

  size_t off = 0;
  char* wsb = (char*)d_ws;
  auto alloc = [&](size_t bytes) -> void* {
    void* p = wsb + off;
    off += (bytes + 255) & ~(size_t)255;
    return p;
  };
  int* bs = (int*)alloc((size_t)NB * 4);
  int* be = (int*)alloc((size_t)NB * 4);
  float* cent = (float*)alloc((size_t)NB * 3 * 4);
  bf16* geom = (bf16*)alloc((size_t)N * 64 * 2);
  float* u = (float*)alloc((size_t)NB * 320 * 4);
  float* cb = (float*)alloc((size_t)NB * 4);
  float* S = (float*)alloc((size_t)NB * 320 * 4);
  float* upd = (float*)alloc((size_t)NB * 256 * 4);
  unsigned short* WqT = (unsigned short*)alloc((size_t)256 * 256 * 2);
  unsigned short* WkC = (unsigned short*)alloc((size_t)320 * 256 * 2);
  unsigned short* WvT = (unsigned short*)alloc((size_t)256 * 320 * 2);
  unsigned short* Wc1T = (unsigned short*)alloc((size_t)256 * 256 * 2);
  unsigned short* Wc2T = (unsigned short*)alloc((size_t)256 * 256 * 2);
  unsigned short* Wf1P = (unsigned short*)alloc((size_t)512 * 256 * 2);
  unsigned short* Wf2P = (unsigned short*)alloc((size_t)256 * 512 * 2);

  hipMemsetAsync(bs, 0, (size_t)NB * 4, stream);
  hipMemsetAsync(be, 0, (size_t)NB * 4, stream);

  // weight preprocessing (tiny)
  tr_k<<<(256 * 256 + 255) / 256, 256, 0, stream>>>(Wq, WqT, 256, 256);
  cast_k<<<(320 * 256 + 255) / 256, 256, 0, stream>>>(Wk, WkC, 320 * 256);
  tr_k<<<(256 * 320 + 255) / 256, 256, 0, stream>>>(Wv, WvT, 320, 256);
  tr_k<<<(256 * 256 + 255) / 256, 256, 0, stream>>>(Wc1, Wc1T, 256, 256);
  tr_k<<<(256 * 256 + 255) / 256, 256, 0, stream>>>(Wc2, Wc2T, 256, 256);
  pack1_k<<<(512 * 256 + 255) / 256, 256, 0, stream>>>(Wf1, Wf1P);
  pack2_k<<<(512 * 256 + 255) / 256, 256, 0, stream>>>(Wf2, Wf2P);

  bounds_k<<<(N + 255) / 256, 256, 0, stream>>>(seg, bs, be, N);
  cent_k<<<(NB + 255) / 256, 256, 0, stream>>>(pos, bs, be, cent, NB);
  geom_k<<<(N + 255) / 256, 256, 0, stream>>>(pos, seg, cent, centers, widths,
                                              Wg, bg, geom, N);
  const int NBB = (NB + 63) / 64;
  blk1_k<<<NBB, 512, 0, stream>>>(bfeat, WqT, bq, WkC, bk, u, cb, NB);
  attn_k<<<(NB + 3) / 4, 256, 0, stream>>>(feat, geom, u, cb, bs, be, S, NB);
  blk2_k<<<NBB, 512, 0, stream>>>(S, WvT, bv, Wc1T, bc1, Wc2T, bc2, upd, NB);
  ffn_mfma_k<<<(N + 63) / 64, 512, 0, stream>>>(feat, seg, upd, Wf1P, bf1_, Wf2P,
                                                bf2_, lng1, lnb1, lng2, lnb2, out, N);
}

// Round 12
// 1065.094 us; speedup vs baseline: 1.4684x; 1.4684x over previous
//
#include <hip/hip_runtime.h>
#include <hip/hip_bf16.h>

// GeometryAwareCrossAttention — round 12:
//  r11 failure branch confirmed: 3 WG/CU infeasible (accC+accB+transients
//  > 85-reg budget -> spill). Operating point is 2 WG/CU at (512,4).
//  ffn_mfma_k structural change on the r10 base: double-buffered f1q
//  (2x[64][128] XOR-swizzled; LDS 48->64KB, still 2 WG/CU) with
//  B(0); bar; { B(q+1) || C(q); bar } x4  -> barriers 8->5 per tile, and
//  next-quarter global weight loads issue before C's MFMAs (latency hides
//  under the matrix pipe).  Everything else = r10 verbatim.

typedef __hip_bfloat16 bf16;
typedef __attribute__((ext_vector_type(8))) short bf16x8;
typedef __attribute__((ext_vector_type(4))) float f32x4;

__device__ __forceinline__ float b2f(bf16 v) { return __bfloat162float(v); }
__device__ __forceinline__ float us2f(unsigned short u) {
  union { unsigned int v; float f; } c; c.v = ((unsigned int)u) << 16; return c.f;
}
__device__ __forceinline__ unsigned short f2bu(float x) {
  bf16 t = __float2bfloat16(x);
  unsigned short u; __builtin_memcpy(&u, &t, 2); return u;
}
__device__ __forceinline__ float4 ld4(const float* p) {
  return *reinterpret_cast<const float4*>(p);
}
__device__ __forceinline__ float4 ldnt4(const float* p) {
  f32x4 v = __builtin_nontemporal_load(reinterpret_cast<const f32x4*>(p));
  return make_float4(v.x, v.y, v.z, v.w);
}
__device__ __forceinline__ float wsum(float v) {
#pragma unroll
  for (int o = 32; o > 0; o >>= 1) v += __shfl_xor(v, o, 64);
  return v;
}
// swizzled LDS fragment read: 8 contiguous bf16 at (row, k), XOR-swizzled.
__device__ __forceinline__ bf16x8 lds_frag(const unsigned short* base, int stride,
                                           int row, int k) {
  return *reinterpret_cast<const bf16x8*>(base + row * stride +
                                          (k ^ ((row & 7) << 3)));
}

// ---------------- segment boundaries (block_id is sorted) ----------------
__global__ void bounds_k(const int* __restrict__ seg, int* __restrict__ bs,
                         int* __restrict__ be, int N) {
  int i = blockIdx.x * 256 + threadIdx.x;
  if (i >= N) return;
  int b = seg[i];
  if (i == 0 || seg[i - 1] != b) bs[b] = i;
  if (i == N - 1 || seg[i + 1] != b) be[b] = i + 1;
}

// ---------------- per-block centroid ----------------
__global__ void cent_k(const float* __restrict__ pos, const int* __restrict__ bs,
                       const int* __restrict__ be, float* __restrict__ cent, int NB) {
  int b = blockIdx.x * 256 + threadIdx.x;
  if (b >= NB) return;
  int s0 = bs[b], s1 = be[b];
  float sx = 0.f, sy = 0.f, sz = 0.f;
  for (int i = s0; i < s1; ++i) {
    sx += pos[(size_t)i * 3 + 0];
    sy += pos[(size_t)i * 3 + 1];
    sz += pos[(size_t)i * 3 + 2];
  }
  float inv = 1.f / fmaxf((float)(s1 - s0), 1.f);
  cent[(size_t)b * 3 + 0] = sx * inv;
  cent[(size_t)b * 3 + 1] = sy * inv;
  cent[(size_t)b * 3 + 2] = sz * inv;
}

// ---------------- per-atom RBF -> geom [N,64] (bf16 scratch) --------------
__global__ __launch_bounds__(256) void geom_k(
    const float* __restrict__ pos, const int* __restrict__ seg,
    const float* __restrict__ cent, const float* __restrict__ centers,
    const float* __restrict__ widths, const float* __restrict__ Wg,
    const float* __restrict__ bg, bf16* __restrict__ geom, int N) {
  __shared__ float sWg[16][64];
  __shared__ float sc[16], sw[16], sbg[64];
  int t = threadIdx.x;
  if (t < 16) {
    sc[t] = centers[t];
    float w = widths[t];
    sw[t] = 1.f / (2.f * w * w);
  }
  for (int j = t; j < 1024; j += 256) sWg[j >> 6][j & 63] = Wg[j];
  if (t < 64) sbg[t] = bg[t];
  __syncthreads();
  int i = blockIdx.x * 256 + t;
  if (i >= N) return;
  int b = seg[i];
  float dx = pos[(size_t)i * 3 + 0] - cent[(size_t)b * 3 + 0];
  float dy = pos[(size_t)i * 3 + 1] - cent[(size_t)b * 3 + 1];
  float dz = pos[(size_t)i * 3 + 2] - cent[(size_t)b * 3 + 2];
  float d = sqrtf(dx * dx + dy * dy + dz * dz);
  float r[16];
#pragma unroll
  for (int j = 0; j < 16; ++j) {
    float dd = d - sc[j];
    r[j] = expf(-dd * dd * sw[j]);
  }
  bf16* gp = geom + (size_t)i * 64;
  for (int g0 = 0; g0 < 64; g0 += 4) {
    float a0 = sbg[g0], a1 = sbg[g0 + 1], a2 = sbg[g0 + 2], a3 = sbg[g0 + 3];
#pragma unroll
    for (int j = 0; j < 16; ++j) {
      float rj = r[j];
      a0 += rj * sWg[j][g0];
      a1 += rj * sWg[j][g0 + 1];
      a2 += rj * sWg[j][g0 + 2];
      a3 += rj * sWg[j][g0 + 3];
    }
    ushort4 o;
    o.x = f2bu(a0); o.y = f2bu(a1); o.z = f2bu(a2); o.w = f2bu(a3);
    *reinterpret_cast<ushort4*>(gp + g0) = o;
  }
}

// ---------------- weight transpose+cast: out[n*K+k] = bf16(in[k*N+n]) -----
__global__ void tr_k(const float* __restrict__ in, unsigned short* __restrict__ out,
                     int K, int N) {
  int idx = blockIdx.x * 256 + threadIdx.x;
  if (idx >= N * K) return;
  int n = idx / K, k = idx % K;
  out[idx] = f2bu(in[(size_t)k * N + n]);
}
// plain cast
__global__ void cast_k(const float* __restrict__ in, unsigned short* __restrict__ out,
                       int n) {
  int idx = blockIdx.x * 256 + threadIdx.x;
  if (idx < n) out[idx] = f2bu(in[idx]);
}

// ---- MFMA-fragment packing for FFN weights (r7 16x16 layout) ----
__global__ void pack1_k(const float* __restrict__ Wf1,
                        unsigned short* __restrict__ P) {
  int idx = blockIdx.x * 256 + threadIdx.x;
  if (idx >= 512 * 256) return;
  int e = idx & 7;
  int l = (idx >> 3) & 63;
  int blk = idx >> 9;
  int ks = blk & 7, wv = (blk >> 3) & 7, q = blk >> 6;
  int n = q * 128 + wv * 16 + (l & 15);
  int k = ks * 32 + (l >> 4) * 8 + e;
  P[idx] = f2bu(Wf1[(size_t)k * 512 + n]);
}
__global__ void pack2_k(const float* __restrict__ Wf2,
                        unsigned short* __restrict__ P) {
  int idx = blockIdx.x * 256 + threadIdx.x;
  if (idx >= 512 * 256) return;
  int e = idx & 7;
  int l = (idx >> 3) & 63;
  int blk = idx >> 9;
  int ks = blk & 3, q = (blk >> 2) & 3, nt = (blk >> 4) & 1, wv = blk >> 5;
  int n = wv * 32 + nt * 16 + (l & 15);
  int k = q * 128 + ks * 32 + (l >> 4) * 8 + e;
  P[idx] = f2bu(Wf2[(size_t)k * 256 + n]);
}

// ---------------- blk1: Q = bfeat@WqT+bq (LDS only); u = Q@Wk^T; cb = Q.bk -
__global__ __launch_bounds__(512, 4) void blk1_k(
    const float* __restrict__ bfeat, const unsigned short* __restrict__ WqT,
    const float* __restrict__ bq, const unsigned short* __restrict__ WkC,
    const float* __restrict__ bk, float* __restrict__ u, float* __restrict__ cb,
    int NB) {
  __shared__ unsigned short x_lds[64 * 256];  // 32 KiB
  __shared__ unsigned short q_lds[64 * 256];  // 32 KiB
  const int t = threadIdx.x;
  const int lane = t & 63, wv = t >> 6, l15 = lane & 15, lhi = lane >> 4;
  const int r0 = blockIdx.x * 64;
  for (int rr = 0; rr < 8; ++rr) {
    int r = wv * 8 + rr;
    int row = r0 + r; if (row >= NB) row = NB - 1;
    float4 v = ldnt4(bfeat + (size_t)row * 256 + lane * 4);
    ushort4 o; o.x = f2bu(v.x); o.y = f2bu(v.y); o.z = f2bu(v.z); o.w = f2bu(v.w);
    *reinterpret_cast<ushort4*>(&x_lds[r * 256 + ((lane * 4) ^ ((r & 7) << 3))]) = o;
  }
  __syncthreads();
  {
    f32x4 acc[2][4];
#pragma unroll
    for (int nt = 0; nt < 2; ++nt)
#pragma unroll
      for (int rt = 0; rt < 4; ++rt) acc[nt][rt] = (f32x4){0.f, 0.f, 0.f, 0.f};
#pragma unroll
    for (int ks = 0; ks < 8; ++ks) {
      bf16x8 a[4];
#pragma unroll
      for (int rt = 0; rt < 4; ++rt)
        a[rt] = lds_frag(x_lds, 256, rt * 16 + l15, ks * 32 + lhi * 8);
#pragma unroll
      for (int nt = 0; nt < 2; ++nt) {
        bf16x8 b = *reinterpret_cast<const bf16x8*>(
            WqT + (size_t)(wv * 32 + nt * 16 + l15) * 256 + ks * 32 + lhi * 8);
#pragma unroll
        for (int rt = 0; rt < 4; ++rt)
          acc[nt][rt] = __builtin_amdgcn_mfma_f32_16x16x32_bf16(a[rt], b, acc[nt][rt], 0, 0, 0);
      }
    }
#pragma unroll
    for (int nt = 0; nt < 2; ++nt) {
      int col = wv * 32 + nt * 16 + l15;
      float bb = bq[col];
#pragma unroll
      for (int rt = 0; rt < 4; ++rt)
#pragma unroll
        for (int j = 0; j < 4; ++j) {
          int row = rt * 16 + lhi * 4 + j;
          q_lds[row * 256 + (col ^ ((row & 7) << 3))] = f2bu(acc[nt][rt][j] + bb);
        }
    }
  }
  __syncthreads();
  if (t < 64) {
    float a = 0.f;
    for (int c = 0; c < 256; ++c)
      a += us2f(q_lds[t * 256 + (c ^ ((t & 7) << 3))]) * bk[c];
    int row = r0 + t;
    if (row < NB) cb[row] = a;
  }
  for (int j = 0; j < 3; ++j) {
    int tile = wv + 8 * j;
    if (tile >= 20) break;
    f32x4 acc[4];
#pragma unroll
    for (int rt = 0; rt < 4; ++rt) acc[rt] = (f32x4){0.f, 0.f, 0.f, 0.f};
#pragma unroll
    for (int ks = 0; ks < 8; ++ks) {
      bf16x8 b = *reinterpret_cast<const bf16x8*>(
          WkC + (size_t)(tile * 16 + l15) * 256 + ks * 32 + lhi * 8);
#pragma unroll
      for (int rt = 0; rt < 4; ++rt) {
        bf16x8 a = lds_frag(q_lds, 256, rt * 16 + l15, ks * 32 + lhi * 8);
        acc[rt] = __builtin_amdgcn_mfma_f32_16x16x32_bf16(a, b, acc[rt], 0, 0, 0);
      }
    }
    int n = tile * 16 + l15;
#pragma unroll
    for (int rt = 0; rt < 4; ++rt)
#pragma unroll
      for (int jj = 0; jj < 4; ++jj) {
        int row = r0 + rt * 16 + lhi * 4 + jj;
        if (row < NB) u[(size_t)row * 320 + n] = acc[rt][jj];
      }
  }
}

// ---------------- segment attention: branchless softmax (no max) ----------
__global__ __launch_bounds__(256) void attn_k(
    const float* __restrict__ feat, const bf16* __restrict__ geom,
    const float* __restrict__ u, const float* __restrict__ cbArr,
    const int* __restrict__ bs, const int* __restrict__ be,
    float* __restrict__ S, int NB) {
  int wave = threadIdx.x >> 6;
  int lane = threadIdx.x & 63;
  int b = blockIdx.x * 4 + wave;
  if (b >= NB) return;
  int s0 = bs[b], s1 = be[b];
  if (s1 <= s0) return;  // empty block: S row never consumed downstream
  const float* ub = u + (size_t)b * 320;
  float4 uv = ld4(ub + lane * 4);
  float ug = ub[256 + lane];
  float cb = cbArr[b];
  const float scale = 0.0625f;  // 1/sqrt(256)
  float l = 0.f;
  float a0 = 0.f, a1 = 0.f, a2 = 0.f, a3 = 0.f, ag = 0.f;
  for (int i = s0; i < s1; ++i) {
    float4 f = ldnt4(feat + (size_t)i * 256 + lane * 4);
    float gm = b2f(geom[(size_t)i * 64 + lane]);
    float p = f.x * uv.x + f.y * uv.y + f.z * uv.z + f.w * uv.w + gm * ug;
    p = wsum(p);
    float e = __expf((p + cb) * scale);  // wave-uniform
    l += e;
    a0 += e * f.x; a1 += e * f.y; a2 += e * f.z; a3 += e * f.w;
    ag += e * gm;
  }
  float inv = 1.f / l;
  float* Sb = S + (size_t)b * 320;
  Sb[lane * 4 + 0] = a0 * inv; Sb[lane * 4 + 1] = a1 * inv;
  Sb[lane * 4 + 2] = a2 * inv; Sb[lane * 4 + 3] = a3 * inv;
  Sb[256 + lane] = ag * inv;
}

// ---------------- blk2: ctx = S@Wv+bv; t1 = relu(ctx@Wc1+bc1); upd = t1@Wc2+bc2
__global__ __launch_bounds__(512, 4) void blk2_k(
    const float* __restrict__ S, const unsigned short* __restrict__ WvT,
    const float* __restrict__ bv, const unsigned short* __restrict__ Wc1T,
    const float* __restrict__ bc1, const unsigned short* __restrict__ Wc2T,
    const float* __restrict__ bc2, float* __restrict__ upd, int NB) {
  __shared__ unsigned short s_lds[64 * 320];  // 40 KiB
  const int t = threadIdx.x;
  const int lane = t & 63, wv = t >> 6, l15 = lane & 15, lhi = lane >> 4;
  const int r0 = blockIdx.x * 64;
  for (int rr = 0; rr < 8; ++rr) {
    int r = wv * 8 + rr;
    int row = r0 + r; if (row >= NB) row = NB - 1;
    float4 v = ld4(S + (size_t)row * 320 + lane * 4);
    ushort4 o; o.x = f2bu(v.x); o.y = f2bu(v.y); o.z = f2bu(v.z); o.w = f2bu(v.w);
    *reinterpret_cast<ushort4*>(&s_lds[r * 320 + ((lane * 4) ^ ((r & 7) << 3))]) = o;
    float g = S[(size_t)row * 320 + 256 + lane];
    s_lds[r * 320 + ((256 + lane) ^ ((r & 7) << 3))] = f2bu(g);
  }
  __syncthreads();
  f32x4 acc[2][4];
#pragma unroll
  for (int nt = 0; nt < 2; ++nt)
#pragma unroll
    for (int rt = 0; rt < 4; ++rt) acc[nt][rt] = (f32x4){0.f, 0.f, 0.f, 0.f};
#pragma unroll
  for (int ks = 0; ks < 10; ++ks) {
    bf16x8 a[4];
#pragma unroll
    for (int rt = 0; rt < 4; ++rt)
      a[rt] = lds_frag(s_lds, 320, rt * 16 + l15, ks * 32 + lhi * 8);
#pragma unroll
    for (int nt = 0; nt < 2; ++nt) {
      bf16x8 b = *reinterpret_cast<const bf16x8*>(
          WvT + (size_t)(wv * 32 + nt * 16 + l15) * 320 + ks * 32 + lhi * 8);
#pragma unroll
      for (int rt = 0; rt < 4; ++rt)
        acc[nt][rt] = __builtin_amdgcn_mfma_f32_16x16x32_bf16(a[rt], b, acc[nt][rt], 0, 0, 0);
    }
  }
  __syncthreads();
#pragma unroll
  for (int nt = 0; nt < 2; ++nt) {
    int col = wv * 32 + nt * 16 + l15;
    float bb = bv[col];
#pragma unroll
    for (int rt = 0; rt < 4; ++rt)
#pragma unroll
      for (int j = 0; j < 4; ++j) {
        int row = rt * 16 + lhi * 4 + j;
        s_lds[row * 256 + (col ^ ((row & 7) << 3))] = f2bu(acc[nt][rt][j] + bb);
      }
  }
  __syncthreads();
#pragma unroll
  for (int nt = 0; nt < 2; ++nt)
#pragma unroll
    for (int rt = 0; rt < 4; ++rt) acc[nt][rt] = (f32x4){0.f, 0.f, 0.f, 0.f};
#pragma unroll
  for (int ks = 0; ks < 8; ++ks) {
    bf16x8 a[4];
#pragma unroll
    for (int rt = 0; rt < 4; ++rt)
      a[rt] = lds_frag(s_lds, 256, rt * 16 + l15, ks * 32 + lhi * 8);
#pragma unroll
    for (int nt = 0; nt < 2; ++nt) {
      bf16x8 b = *reinterpret_cast<const bf16x8*>(
          Wc1T + (size_t)(wv * 32 + nt * 16 + l15) * 256 + ks * 32 + lhi * 8);
#pragma unroll
      for (int rt = 0; rt < 4; ++rt)
        acc[nt][rt] = __builtin_amdgcn_mfma_f32_16x16x32_bf16(a[rt], b, acc[nt][rt], 0, 0, 0);
    }
  }
  __syncthreads();
#pragma unroll
  for (int nt = 0; nt < 2; ++nt) {
    int col = wv * 32 + nt * 16 + l15;
    float bb = bc1[col];
#pragma unroll
    for (int rt = 0; rt < 4; ++rt)
#pragma unroll
      for (int j = 0; j < 4; ++j) {
        int row = rt * 16 + lhi * 4 + j;
        s_lds[row * 256 + (col ^ ((row & 7) << 3))] = f2bu(fmaxf(acc[nt][rt][j] + bb, 0.f));
      }
  }
  __syncthreads();
#pragma unroll
  for (int nt = 0; nt < 2; ++nt)
#pragma unroll
    for (int rt = 0; rt < 4; ++rt) acc[nt][rt] = (f32x4){0.f, 0.f, 0.f, 0.f};
#pragma unroll
  for (int ks = 0; ks < 8; ++ks) {
    bf16x8 a[4];
#pragma unroll
    for (int rt = 0; rt < 4; ++rt)
      a[rt] = lds_frag(s_lds, 256, rt * 16 + l15, ks * 32 + lhi * 8);
#pragma unroll
    for (int nt = 0; nt < 2; ++nt) {
      bf16x8 b = *reinterpret_cast<const bf16x8*>(
          Wc2T + (size_t)(wv * 32 + nt * 16 + l15) * 256 + ks * 32 + lhi * 8);
#pragma unroll
      for (int rt = 0; rt < 4; ++rt)
        acc[nt][rt] = __builtin_amdgcn_mfma_f32_16x16x32_bf16(a[rt], b, acc[nt][rt], 0, 0, 0);
    }
  }
#pragma unroll
  for (int nt = 0; nt < 2; ++nt) {
    int col = wv * 32 + nt * 16 + l15;
    float bb = bc2[col];
#pragma unroll
    for (int rt = 0; rt < 4; ++rt)
#pragma unroll
      for (int j = 0; j < 4; ++j) {
        int row = r0 + rt * 16 + lhi * 4 + j;
        if (row < NB) upd[(size_t)row * 256 + col] = acc[nt][rt][j] + bb;
      }
  }
}

// ---------------- fused LN1 -> FFN(MFMA, dbuf quarter pipeline) -> LN2 ----
// 512 thr = 8 waves; LDS: h[64][256] 32K + 2x f1q[64][128] 32K = 64KB.
// Schedule: B(0); bar; { B(q+1) || C(q); bar } x4  (5 barriers, B/C overlap).
__global__ __launch_bounds__(512, 4) void ffn_mfma_k(
    const float* __restrict__ feat, const int* __restrict__ seg,
    const float* __restrict__ upd, const unsigned short* __restrict__ Wf1P,
    const float* __restrict__ bf1_, const unsigned short* __restrict__ Wf2P,
    const float* __restrict__ bf2_, const float* __restrict__ lng1,
    const float* __restrict__ lnb1, const float* __restrict__ lng2,
    const float* __restrict__ lnb2, float* __restrict__ out, int N) {
  __shared__ unsigned short h_lds[64 * 256];       // h, later y = h + ffn2
  __shared__ unsigned short f1q_lds[2][64 * 128];  // double-buffered quarter
  const int t = threadIdx.x;
  const int lane = t & 63;
  const int wv = t >> 6;
  const int l15 = lane & 15;
  const int lhi = lane >> 4;
  const int r0 = blockIdx.x * 64;

  // ---- phase A: h = LN1(feat + upd[seg]) -> bf16 swizzled LDS ----
  {
    float4 g1v = ld4(lng1 + lane * 4);
    float4 b1v = ld4(lnb1 + lane * 4);
    for (int rr = 0; rr < 8; ++rr) {
      int r = wv * 8 + rr;
      int row = r0 + r;
      if (row >= N) row = N - 1;
      int bidx = seg[row];
      float4 xf = ldnt4(feat + (size_t)row * 256 + lane * 4);
      float4 up = ld4(upd + (size_t)bidx * 256 + lane * 4);
      float x0 = xf.x + up.x, x1 = xf.y + up.y;
      float x2 = xf.z + up.z, x3 = xf.w + up.w;
      float s = wsum(x0 + x1 + x2 + x3);
      float s2 = wsum(x0 * x0 + x1 * x1 + x2 * x2 + x3 * x3);
      float mean = s * (1.f / 256.f);
      float var = s2 * (1.f / 256.f) - mean * mean;
      float rstd = rsqrtf(var + 1e-5f);
      ushort4 o;
      o.x = f2bu((x0 - mean) * rstd * g1v.x + b1v.x);
      o.y = f2bu((x1 - mean) * rstd * g1v.y + b1v.y);
      o.z = f2bu((x2 - mean) * rstd * g1v.z + b1v.z);
      o.w = f2bu((x3 - mean) * rstd * g1v.w + b1v.w);
      *reinterpret_cast<ushort4*>(&h_lds[r * 256 + ((lane * 4) ^ ((r & 7) << 3))]) = o;
    }
  }
  __syncthreads();

  f32x4 accC[2][4];
#pragma unroll
  for (int nt = 0; nt < 2; ++nt)
#pragma unroll
    for (int rt = 0; rt < 4; ++rt) accC[nt][rt] = (f32x4){0.f, 0.f, 0.f, 0.f};

  // phase B for quarter q -> f1buf (r10-verified body)
  auto phaseB = [&](int q, unsigned short* f1buf) {
    f32x4 accB[4];
#pragma unroll
    for (int rt = 0; rt < 4; ++rt) accB[rt] = (f32x4){0.f, 0.f, 0.f, 0.f};
    const unsigned short* wb =
        Wf1P + (size_t)((q * 8 + wv) * 8) * 512 + lane * 8;
    bf16x8 bcur = *reinterpret_cast<const bf16x8*>(wb);
#pragma unroll
    for (int ks = 0; ks < 8; ++ks) {
      bf16x8 bnx = bcur;
      if (ks < 7) bnx = *reinterpret_cast<const bf16x8*>(wb + (ks + 1) * 512);
      int k = ks * 32 + lhi * 8;
      bf16x8 a0 = lds_frag(h_lds, 256, 0 * 16 + l15, k);
      bf16x8 a1 = lds_frag(h_lds, 256, 1 * 16 + l15, k);
      bf16x8 a2 = lds_frag(h_lds, 256, 2 * 16 + l15, k);
      bf16x8 a3 = lds_frag(h_lds, 256, 3 * 16 + l15, k);
      accB[0] = __builtin_amdgcn_mfma_f32_16x16x32_bf16(a0, bcur, accB[0], 0, 0, 0);
      accB[1] = __builtin_amdgcn_mfma_f32_16x16x32_bf16(a1, bcur, accB[1], 0, 0, 0);
      accB[2] = __builtin_amdgcn_mfma_f32_16x16x32_bf16(a2, bcur, accB[2], 0, 0, 0);
      accB[3] = __builtin_amdgcn_mfma_f32_16x16x32_bf16(a3, bcur, accB[3], 0, 0, 0);
      bcur = bnx;
    }
    int coll = wv * 16 + l15;
    float bb = bf1_[q * 128 + coll];
#pragma unroll
    for (int rt = 0; rt < 4; ++rt)
#pragma unroll
      for (int j = 0; j < 4; ++j) {
        int row = rt * 16 + lhi * 4 + j;
        f1buf[row * 128 + (coll ^ ((row & 7) << 3))] =
            f2bu(fmaxf(accB[rt][j] + bb, 0.f));
      }
  };
  // phase C for quarter q from f1buf
  auto phaseC = [&](int q, const unsigned short* f1buf) {
#pragma unroll
    for (int ks = 0; ks < 4; ++ks) {
      int k = ks * 32 + lhi * 8;
      bf16x8 a0 = lds_frag(f1buf, 128, 0 * 16 + l15, k);
      bf16x8 a1 = lds_frag(f1buf, 128, 1 * 16 + l15, k);
      bf16x8 a2 = lds_frag(f1buf, 128, 2 * 16 + l15, k);
      bf16x8 a3 = lds_frag(f1buf, 128, 3 * 16 + l15, k);
#pragma unroll
      for (int nt = 0; nt < 2; ++nt) {
        bf16x8 b = *reinterpret_cast<const bf16x8*>(
            Wf2P + (size_t)((wv * 2 + nt) * 16 + q * 4 + ks) * 512 + lane * 8);
        accC[nt][0] = __builtin_amdgcn_mfma_f32_16x16x32_bf16(a0, b, accC[nt][0], 0, 0, 0);
        accC[nt][1] = __builtin_amdgcn_mfma_f32_16x16x32_bf16(a1, b, accC[nt][1], 0, 0, 0);
        accC[nt][2] = __builtin_amdgcn_mfma_f32_16x16x32_bf16(a2, b, accC[nt][2], 0, 0, 0);
        accC[nt][3] = __builtin_amdgcn_mfma_f32_16x16x32_bf16(a3, b, accC[nt][3], 0, 0, 0);
      }
    }
  };

  phaseB(0, f1q_lds[0]);
  __syncthreads();
#pragma unroll 1
  for (int q = 0; q < 4; ++q) {
    if (q < 3) phaseB(q + 1, f1q_lds[(q + 1) & 1]);  // next quarter (other buf)
    phaseC(q, f1q_lds[q & 1]);                        // current quarter
    __syncthreads();
  }

  // ---- y = h + ffn2 + bf2, in place in h_lds ----
#pragma unroll
  for (int nt = 0; nt < 2; ++nt) {
    int c = wv * 32 + nt * 16 + l15;
    float bb = bf2_[c];
#pragma unroll
    for (int rt = 0; rt < 4; ++rt)
#pragma unroll
      for (int j = 0; j < 4; ++j) {
        int row = rt * 16 + lhi * 4 + j;
        int idx = row * 256 + (c ^ ((row & 7) << 3));
        h_lds[idx] = f2bu(us2f(h_lds[idx]) + accC[nt][rt][j] + bb);
      }
  }
  __syncthreads();

  // ---- LN2(y) -> out (plain cached store) ----
  {
    float4 g2v = ld4(lng2 + lane * 4);
    float4 b2v = ld4(lnb2 + lane * 4);
    for (int rr = 0; rr < 8; ++rr) {
      int r = wv * 8 + rr;
      int row = r0 + r;
      if (row >= N) row = N - 1;
      int idx = r * 256 + ((lane * 4) ^ ((r & 7) << 3));
      ushort4 yv = *reinterpret_cast<const ushort4*>(&h_lds[idx]);
      float y0 = us2f(yv.x), y1 = us2f(yv.y), y2 = us2f(yv.z), y3 = us2f(yv.w);
      float s = wsum(y0 + y1 + y2 + y3);
      float s2 = wsum(y0 * y0 + y1 * y1 + y2 * y2 + y3 * y3);
      float mean = s * (1.f / 256.f);
      float var = s2 * (1.f / 256.f) - mean * mean;
      float rstd = rsqrtf(var + 1e-5f);
      float4 o;
      o.x = (y0 - mean) * rstd * g2v.x + b2v.x;
      o.y = (y1 - mean) * rstd * g2v.y + b2v.y;
      o.z = (y2 - mean) * rstd * g2v.z + b2v.z;
      o.w = (y3 - mean) * rstd * g2v.w + b2v.w;
      *reinterpret_cast<float4*>(out + (size_t)row * 256 + lane * 4) = o;
    }
  }
}

extern "C" void kernel_launch(void* const* d_in, const int* in_sizes, int n_in,
                              void* d_out, int out_size, void* d_ws, size_t ws_size,
                              hipStream_t stream) {
  const float* feat = (const float*)d_in[0];
  const float* pos = (const float*)d_in[1];
  const float* bfeat = (const float*)d_in[2];
  const int* seg = (const int*)d_in[3];
  const float* centers = (const float*)d_in[4];
  const float* widths = (const float*)d_in[5];
  const float* Wg = (const float*)d_in[6];
  const float* bg = (const float*)d_in[7];
  const float* Wq = (const float*)d_in[8];
  const float* bq = (const float*)d_in[9];
  const float* Wk = (const float*)d_in[10];
  const float* bk = (const float*)d_in[11];
  const float* Wv = (const float*)d_in[12];
  const float* bv = (const float*)d_in[13];
  const float* Wc1 = (const float*)d_in[14];
  const float* bc1 = (const float*)d_in[15];
  const float* Wc2 = (const float*)d_in[16];
  const float* bc2 = (const float*)d_in[17];
  const float* Wf1 = (const float*)d_in[18];
  const float* bf1_ = (const float*)d_in[19];
  const float* Wf2 = (const float*)d_in[20];
  const float* bf2_ = (const float*)d_in[21];
  const float* lng1 = (const float*)d_in[22];
  const float* lnb1 = (const float*)d_in[23];
  const float* lng2 = (const float*)d_in[24];
  const float* lnb2 = (const float*)d_in[25];
  float* out = (float*)d_out;

  const int N = in_sizes[0] / 256;   // 500000
  const int NB = in_sizes[2] / 256;  // 50000

  size_t off = 0;
  char* wsb = (char*)d_ws;
  auto alloc = [&](size_t bytes) -> void* {
    void* p = wsb + off;
    off += (bytes + 255) & ~(size_t)255;
    return p;
  };
  int* bs = (int*)alloc((size_t)NB * 4);
  int* be = (int*)alloc((size_t)NB * 4);
  float* cent = (float*)alloc((size_t)NB * 3 * 4);
  bf16* geom = (bf16*)alloc((size_t)N * 64 * 2);
  float* u = (float*)alloc((size_t)NB * 320 * 4);
  float* cb = (float*)alloc((size_t)NB * 4);
  float* S = (float*)alloc((size_t)NB * 320 * 4);
  float* upd = (float*)alloc((size_t)NB * 256 * 4);
  unsigned short* WqT = (unsigned short*)alloc((size_t)256 * 256 * 2);
  unsigned short* WkC = (unsigned short*)alloc((size_t)320 * 256 * 2);
  unsigned short* WvT = (unsigned short*)alloc((size_t)256 * 320 * 2);
  unsigned short* Wc1T = (unsigned short*)alloc((size_t)256 * 256 * 2);
  unsigned short* Wc2T = (unsigned short*)alloc((size_t)256 * 256 * 2);
  unsigned short* Wf1P = (unsigned short*)alloc((size_t)512 * 256 * 2);
  unsigned short* Wf2P = (unsigned short*)alloc((size_t)256 * 512 * 2);

  hipMemsetAsync(bs, 0, (size_t)NB * 4, stream);
  hipMemsetAsync(be, 0, (size_t)NB * 4, stream);

  // weight preprocessing (tiny)
  tr_k<<<(256 * 256 + 255) / 256, 256, 0, stream>>>(Wq, WqT, 256, 256);
  cast_k<<<(320 * 256 + 255) / 256, 256, 0, stream>>>(Wk, WkC, 320 * 256);
  tr_k<<<(256 * 320 + 255) / 256, 256, 0, stream>>>(Wv, WvT, 320, 256);
  tr_k<<<(256 * 256 + 255) / 256, 256, 0, stream>>>(Wc1, Wc1T, 256, 256);
  tr_k<<<(256 * 256 + 255) / 256, 256, 0, stream>>>(Wc2, Wc2T, 256, 256);
  pack1_k<<<(512 * 256 + 255) / 256, 256, 0, stream>>>(Wf1, Wf1P);
  pack2_k<<<(512 * 256 + 255) / 256, 256, 0, stream>>>(Wf2, Wf2P);

  bounds_k<<<(N + 255) / 256, 256, 0, stream>>>(seg, bs, be, N);
  cent_k<<<(NB + 255) / 256, 256, 0, stream>>>(pos, bs, be, cent, NB);
  geom_k<<<(N + 255) / 256, 256, 0, stream>>>(pos, seg, cent, centers, widths,
                                              Wg, bg, geom, N);
  const int NBB = (NB + 63) / 64;
  blk1_k<<<NBB, 512, 0, stream>>>(bfeat, WqT, bq, WkC, bk, u, cb, NB);
  attn_k<<<(NB + 3) / 4, 256, 0, stream>>>(feat, geom, u, cb, bs, be, S, NB);
  blk2_k<<<NBB, 512, 0, stream>>>(S, WvT, bv, Wc1T, bc1, Wc2T, bc2, upd, NB);
  ffn_mfma_k<<<(N + 63) / 64, 512, 0, stream>>>(feat, seg, upd, Wf1P, bf1_, Wf2P,
                                                bf2_, lng1, lnb1, lng2, lnb2, out, N);
}

// Round 13
// 996.343 us; speedup vs baseline: 1.5697x; 1.0690x over previous
//
#include <hip/hip_runtime.h>
#include <hip/hip_bf16.h>

// GeometryAwareCrossAttention — round 13:
//  * ffn_mfma_k: EXACT r10 revert (617us twice-reproduced; r12's dbuf overlap
//    spilled: accB+accC+dual-phase transients > 128-reg budget).
//  * attn_k: 2-atom unroll with interleaved __shfl_xor reduction chains —
//    the per-atom 6-step dependent shuffle chain was the pace-setter; two
//    independent chains pipeline and halve exposed latency.
//  Everything else = r10 verbatim.

typedef __hip_bfloat16 bf16;
typedef __attribute__((ext_vector_type(8))) short bf16x8;
typedef __attribute__((ext_vector_type(4))) float f32x4;

__device__ __forceinline__ float b2f(bf16 v) { return __bfloat162float(v); }
__device__ __forceinline__ float us2f(unsigned short u) {
  union { unsigned int v; float f; } c; c.v = ((unsigned int)u) << 16; return c.f;
}
__device__ __forceinline__ unsigned short f2bu(float x) {
  bf16 t = __float2bfloat16(x);
  unsigned short u; __builtin_memcpy(&u, &t, 2); return u;
}
__device__ __forceinline__ float4 ld4(const float* p) {
  return *reinterpret_cast<const float4*>(p);
}
__device__ __forceinline__ float4 ldnt4(const float* p) {
  f32x4 v = __builtin_nontemporal_load(reinterpret_cast<const f32x4*>(p));
  return make_float4(v.x, v.y, v.z, v.w);
}
__device__ __forceinline__ float wsum(float v) {
#pragma unroll
  for (int o = 32; o > 0; o >>= 1) v += __shfl_xor(v, o, 64);
  return v;
}
// swizzled LDS fragment read: 8 contiguous bf16 at (row, k), XOR-swizzled.
__device__ __forceinline__ bf16x8 lds_frag(const unsigned short* base, int stride,
                                           int row, int k) {
  return *reinterpret_cast<const bf16x8*>(base + row * stride +
                                          (k ^ ((row & 7) << 3)));
}

// ---------------- segment boundaries (block_id is sorted) ----------------
__global__ void bounds_k(const int* __restrict__ seg, int* __restrict__ bs,
                         int* __restrict__ be, int N) {
  int i = blockIdx.x * 256 + threadIdx.x;
  if (i >= N) return;
  int b = seg[i];
  if (i == 0 || seg[i - 1] != b) bs[b] = i;
  if (i == N - 1 || seg[i + 1] != b) be[b] = i + 1;
}

// ---------------- per-block centroid ----------------
__global__ void cent_k(const float* __restrict__ pos, const int* __restrict__ bs,
                       const int* __restrict__ be, float* __restrict__ cent, int NB) {
  int b = blockIdx.x * 256 + threadIdx.x;
  if (b >= NB) return;
  int s0 = bs[b], s1 = be[b];
  float sx = 0.f, sy = 0.f, sz = 0.f;
  for (int i = s0; i < s1; ++i) {
    sx += pos[(size_t)i * 3 + 0];
    sy += pos[(size_t)i * 3 + 1];
    sz += pos[(size_t)i * 3 + 2];
  }
  float inv = 1.f / fmaxf((float)(s1 - s0), 1.f);
  cent[(size_t)b * 3 + 0] = sx * inv;
  cent[(size_t)b * 3 + 1] = sy * inv;
  cent[(size_t)b * 3 + 2] = sz * inv;
}

// ---------------- per-atom RBF -> geom [N,64] (bf16 scratch) --------------
__global__ __launch_bounds__(256) void geom_k(
    const float* __restrict__ pos, const int* __restrict__ seg,
    const float* __restrict__ cent, const float* __restrict__ centers,
    const float* __restrict__ widths, const float* __restrict__ Wg,
    const float* __restrict__ bg, bf16* __restrict__ geom, int N) {
  __shared__ float sWg[16][64];
  __shared__ float sc[16], sw[16], sbg[64];
  int t = threadIdx.x;
  if (t < 16) {
    sc[t] = centers[t];
    float w = widths[t];
    sw[t] = 1.f / (2.f * w * w);
  }
  for (int j = t; j < 1024; j += 256) sWg[j >> 6][j & 63] = Wg[j];
  if (t < 64) sbg[t] = bg[t];
  __syncthreads();
  int i = blockIdx.x * 256 + t;
  if (i >= N) return;
  int b = seg[i];
  float dx = pos[(size_t)i * 3 + 0] - cent[(size_t)b * 3 + 0];
  float dy = pos[(size_t)i * 3 + 1] - cent[(size_t)b * 3 + 1];
  float dz = pos[(size_t)i * 3 + 2] - cent[(size_t)b * 3 + 2];
  float d = sqrtf(dx * dx + dy * dy + dz * dz);
  float r[16];
#pragma unroll
  for (int j = 0; j < 16; ++j) {
    float dd = d - sc[j];
    r[j] = expf(-dd * dd * sw[j]);
  }
  bf16* gp = geom + (size_t)i * 64;
  for (int g0 = 0; g0 < 64; g0 += 4) {
    float a0 = sbg[g0], a1 = sbg[g0 + 1], a2 = sbg[g0 + 2], a3 = sbg[g0 + 3];
#pragma unroll
    for (int j = 0; j < 16; ++j) {
      float rj = r[j];
      a0 += rj * sWg[j][g0];
      a1 += rj * sWg[j][g0 + 1];
      a2 += rj * sWg[j][g0 + 2];
      a3 += rj * sWg[j][g0 + 3];
    }
    ushort4 o;
    o.x = f2bu(a0); o.y = f2bu(a1); o.z = f2bu(a2); o.w = f2bu(a3);
    *reinterpret_cast<ushort4*>(gp + g0) = o;
  }
}

// ---------------- weight transpose+cast: out[n*K+k] = bf16(in[k*N+n]) -----
__global__ void tr_k(const float* __restrict__ in, unsigned short* __restrict__ out,
                     int K, int N) {
  int idx = blockIdx.x * 256 + threadIdx.x;
  if (idx >= N * K) return;
  int n = idx / K, k = idx % K;
  out[idx] = f2bu(in[(size_t)k * N + n]);
}
// plain cast
__global__ void cast_k(const float* __restrict__ in, unsigned short* __restrict__ out,
                       int n) {
  int idx = blockIdx.x * 256 + threadIdx.x;
  if (idx < n) out[idx] = f2bu(in[idx]);
}

// ---- MFMA-fragment packing for FFN weights (r7 16x16 layout) ----
__global__ void pack1_k(const float* __restrict__ Wf1,
                        unsigned short* __restrict__ P) {
  int idx = blockIdx.x * 256 + threadIdx.x;
  if (idx >= 512 * 256) return;
  int e = idx & 7;
  int l = (idx >> 3) & 63;
  int blk = idx >> 9;
  int ks = blk & 7, wv = (blk >> 3) & 7, q = blk >> 6;
  int n = q * 128 + wv * 16 + (l & 15);
  int k = ks * 32 + (l >> 4) * 8 + e;
  P[idx] = f2bu(Wf1[(size_t)k * 512 + n]);
}
__global__ void pack2_k(const float* __restrict__ Wf2,
                        unsigned short* __restrict__ P) {
  int idx = blockIdx.x * 256 + threadIdx.x;
  if (idx >= 512 * 256) return;
  int e = idx & 7;
  int l = (idx >> 3) & 63;
  int blk = idx >> 9;
  int ks = blk & 3, q = (blk >> 2) & 3, nt = (blk >> 4) & 1, wv = blk >> 5;
  int n = wv * 32 + nt * 16 + (l & 15);
  int k = q * 128 + ks * 32 + (l >> 4) * 8 + e;
  P[idx] = f2bu(Wf2[(size_t)k * 256 + n]);
}

// ---------------- blk1: Q = bfeat@WqT+bq (LDS only); u = Q@Wk^T; cb = Q.bk -
__global__ __launch_bounds__(512, 4) void blk1_k(
    const float* __restrict__ bfeat, const unsigned short* __restrict__ WqT,
    const float* __restrict__ bq, const unsigned short* __restrict__ WkC,
    const float* __restrict__ bk, float* __restrict__ u, float* __restrict__ cb,
    int NB) {
  __shared__ unsigned short x_lds[64 * 256];  // 32 KiB
  __shared__ unsigned short q_lds[64 * 256];  // 32 KiB
  const int t = threadIdx.x;
  const int lane = t & 63, wv = t >> 6, l15 = lane & 15, lhi = lane >> 4;
  const int r0 = blockIdx.x * 64;
  for (int rr = 0; rr < 8; ++rr) {
    int r = wv * 8 + rr;
    int row = r0 + r; if (row >= NB) row = NB - 1;
    float4 v = ldnt4(bfeat + (size_t)row * 256 + lane * 4);
    ushort4 o; o.x = f2bu(v.x); o.y = f2bu(v.y); o.z = f2bu(v.z); o.w = f2bu(v.w);
    *reinterpret_cast<ushort4*>(&x_lds[r * 256 + ((lane * 4) ^ ((r & 7) << 3))]) = o;
  }
  __syncthreads();
  {
    f32x4 acc[2][4];
#pragma unroll
    for (int nt = 0; nt < 2; ++nt)
#pragma unroll
      for (int rt = 0; rt < 4; ++rt) acc[nt][rt] = (f32x4){0.f, 0.f, 0.f, 0.f};
#pragma unroll
    for (int ks = 0; ks < 8; ++ks) {
      bf16x8 a[4];
#pragma unroll
      for (int rt = 0; rt < 4; ++rt)
        a[rt] = lds_frag(x_lds, 256, rt * 16 + l15, ks * 32 + lhi * 8);
#pragma unroll
      for (int nt = 0; nt < 2; ++nt) {
        bf16x8 b = *reinterpret_cast<const bf16x8*>(
            WqT + (size_t)(wv * 32 + nt * 16 + l15) * 256 + ks * 32 + lhi * 8);
#pragma unroll
        for (int rt = 0; rt < 4; ++rt)
          acc[nt][rt] = __builtin_amdgcn_mfma_f32_16x16x32_bf16(a[rt], b, acc[nt][rt], 0, 0, 0);
      }
    }
#pragma unroll
    for (int nt = 0; nt < 2; ++nt) {
      int col = wv * 32 + nt * 16 + l15;
      float bb = bq[col];
#pragma unroll
      for (int rt = 0; rt < 4; ++rt)
#pragma unroll
        for (int j = 0; j < 4; ++j) {
          int row = rt * 16 + lhi * 4 + j;
          q_lds[row * 256 + (col ^ ((row & 7) << 3))] = f2bu(acc[nt][rt][j] + bb);
        }
    }
  }
  __syncthreads();
  if (t < 64) {
    float a = 0.f;
    for (int c = 0; c < 256; ++c)
      a += us2f(q_lds[t * 256 + (c ^ ((t & 7) << 3))]) * bk[c];
    int row = r0 + t;
    if (row < NB) cb[row] = a;
  }
  for (int j = 0; j < 3; ++j) {
    int tile = wv + 8 * j;
    if (tile >= 20) break;
    f32x4 acc[4];
#pragma unroll
    for (int rt = 0; rt < 4; ++rt) acc[rt] = (f32x4){0.f, 0.f, 0.f, 0.f};
#pragma unroll
    for (int ks = 0; ks < 8; ++ks) {
      bf16x8 b = *reinterpret_cast<const bf16x8*>(
          WkC + (size_t)(tile * 16 + l15) * 256 + ks * 32 + lhi * 8);
#pragma unroll
      for (int rt = 0; rt < 4; ++rt) {
        bf16x8 a = lds_frag(q_lds, 256, rt * 16 + l15, ks * 32 + lhi * 8);
        acc[rt] = __builtin_amdgcn_mfma_f32_16x16x32_bf16(a, b, acc[rt], 0, 0, 0);
      }
    }
    int n = tile * 16 + l15;
#pragma unroll
    for (int rt = 0; rt < 4; ++rt)
#pragma unroll
      for (int jj = 0; jj < 4; ++jj) {
        int row = r0 + rt * 16 + lhi * 4 + jj;
        if (row < NB) u[(size_t)row * 320 + n] = acc[rt][jj];
      }
  }
}

// ---------------- segment attention: branchless softmax, 2-atom unroll ----
__global__ __launch_bounds__(256) void attn_k(
    const float* __restrict__ feat, const bf16* __restrict__ geom,
    const float* __restrict__ u, const float* __restrict__ cbArr,
    const int* __restrict__ bs, const int* __restrict__ be,
    float* __restrict__ S, int NB) {
  int wave = threadIdx.x >> 6;
  int lane = threadIdx.x & 63;
  int b = blockIdx.x * 4 + wave;
  if (b >= NB) return;
  int s0 = bs[b], s1 = be[b];
  if (s1 <= s0) return;  // empty block: S row never consumed downstream
  const float* ub = u + (size_t)b * 320;
  float4 uv = ld4(ub + lane * 4);
  float ug = ub[256 + lane];
  float cb = cbArr[b];
  const float scale = 0.0625f;  // 1/sqrt(256)
  float l = 0.f;
  float a0 = 0.f, a1 = 0.f, a2 = 0.f, a3 = 0.f, ag = 0.f;
  int i = s0;
  for (; i + 1 < s1; i += 2) {
    float4 f0 = ldnt4(feat + (size_t)i * 256 + lane * 4);
    float4 f1 = ldnt4(feat + (size_t)(i + 1) * 256 + lane * 4);
    float g0 = b2f(geom[(size_t)i * 64 + lane]);
    float g1 = b2f(geom[(size_t)(i + 1) * 64 + lane]);
    float p0 = f0.x * uv.x + f0.y * uv.y + f0.z * uv.z + f0.w * uv.w + g0 * ug;
    float p1 = f1.x * uv.x + f1.y * uv.y + f1.z * uv.z + f1.w * uv.w + g1 * ug;
    // two independent reduction chains, interleaved
#pragma unroll
    for (int o = 32; o > 0; o >>= 1) {
      p0 += __shfl_xor(p0, o, 64);
      p1 += __shfl_xor(p1, o, 64);
    }
    float e0 = __expf((p0 + cb) * scale);
    float e1 = __expf((p1 + cb) * scale);
    l += e0 + e1;
    a0 += e0 * f0.x + e1 * f1.x;
    a1 += e0 * f0.y + e1 * f1.y;
    a2 += e0 * f0.z + e1 * f1.z;
    a3 += e0 * f0.w + e1 * f1.w;
    ag += e0 * g0 + e1 * g1;
  }
  if (i < s1) {
    float4 f = ldnt4(feat + (size_t)i * 256 + lane * 4);
    float gm = b2f(geom[(size_t)i * 64 + lane]);
    float p = f.x * uv.x + f.y * uv.y + f.z * uv.z + f.w * uv.w + gm * ug;
    p = wsum(p);
    float e = __expf((p + cb) * scale);
    l += e;
    a0 += e * f.x; a1 += e * f.y; a2 += e * f.z; a3 += e * f.w;
    ag += e * gm;
  }
  float inv = 1.f / l;
  float* Sb = S + (size_t)b * 320;
  Sb[lane * 4 + 0] = a0 * inv; Sb[lane * 4 + 1] = a1 * inv;
  Sb[lane * 4 + 2] = a2 * inv; Sb[lane * 4 + 3] = a3 * inv;
  Sb[256 + lane] = ag * inv;
}

// ---------------- blk2: ctx = S@Wv+bv; t1 = relu(ctx@Wc1+bc1); upd = t1@Wc2+bc2
__global__ __launch_bounds__(512, 4) void blk2_k(
    const float* __restrict__ S, const unsigned short* __restrict__ WvT,
    const float* __restrict__ bv, const unsigned short* __restrict__ Wc1T,
    const float* __restrict__ bc1, const unsigned short* __restrict__ Wc2T,
    const float* __restrict__ bc2, float* __restrict__ upd, int NB) {
  __shared__ unsigned short s_lds[64 * 320];  // 40 KiB
  const int t = threadIdx.x;
  const int lane = t & 63, wv = t >> 6, l15 = lane & 15, lhi = lane >> 4;
  const int r0 = blockIdx.x * 64;
  for (int rr = 0; rr < 8; ++rr) {
    int r = wv * 8 + rr;
    int row = r0 + r; if (row >= NB) row = NB - 1;
    float4 v = ld4(S + (size_t)row * 320 + lane * 4);
    ushort4 o; o.x = f2bu(v.x); o.y = f2bu(v.y); o.z = f2bu(v.z); o.w = f2bu(v.w);
    *reinterpret_cast<ushort4*>(&s_lds[r * 320 + ((lane * 4) ^ ((r & 7) << 3))]) = o;
    float g = S[(size_t)row * 320 + 256 + lane];
    s_lds[r * 320 + ((256 + lane) ^ ((r & 7) << 3))] = f2bu(g);
  }
  __syncthreads();
  f32x4 acc[2][4];
#pragma unroll
  for (int nt = 0; nt < 2; ++nt)
#pragma unroll
    for (int rt = 0; rt < 4; ++rt) acc[nt][rt] = (f32x4){0.f, 0.f, 0.f, 0.f};
#pragma unroll
  for (int ks = 0; ks < 10; ++ks) {
    bf16x8 a[4];
#pragma unroll
    for (int rt = 0; rt < 4; ++rt)
      a[rt] = lds_frag(s_lds, 320, rt * 16 + l15, ks * 32 + lhi * 8);
#pragma unroll
    for (int nt = 0; nt < 2; ++nt) {
      bf16x8 b = *reinterpret_cast<const bf16x8*>(
          WvT + (size_t)(wv * 32 + nt * 16 + l15) * 320 + ks * 32 + lhi * 8);
#pragma unroll
      for (int rt = 0; rt < 4; ++rt)
        acc[nt][rt] = __builtin_amdgcn_mfma_f32_16x16x32_bf16(a[rt], b, acc[nt][rt], 0, 0, 0);
    }
  }
  __syncthreads();
#pragma unroll
  for (int nt = 0; nt < 2; ++nt) {
    int col = wv * 32 + nt * 16 + l15;
    float bb = bv[col];
#pragma unroll
    for (int rt = 0; rt < 4; ++rt)
#pragma unroll
      for (int j = 0; j < 4; ++j) {
        int row = rt * 16 + lhi * 4 + j;
        s_lds[row * 256 + (col ^ ((row & 7) << 3))] = f2bu(acc[nt][rt][j] + bb);
      }
  }
  __syncthreads();
#pragma unroll
  for (int nt = 0; nt < 2; ++nt)
#pragma unroll
    for (int rt = 0; rt < 4; ++rt) acc[nt][rt] = (f32x4){0.f, 0.f, 0.f, 0.f};
#pragma unroll
  for (int ks = 0; ks < 8; ++ks) {
    bf16x8 a[4];
#pragma unroll
    for (int rt = 0; rt < 4; ++rt)
      a[rt] = lds_frag(s_lds, 256, rt * 16 + l15, ks * 32 + lhi * 8);
#pragma unroll
    for (int nt = 0; nt < 2; ++nt) {
      bf16x8 b = *reinterpret_cast<const bf16x8*>(
          Wc1T + (size_t)(wv * 32 + nt * 16 + l15) * 256 + ks * 32 + lhi * 8);
#pragma unroll
      for (int rt = 0; rt < 4; ++rt)
        acc[nt][rt] = __builtin_amdgcn_mfma_f32_16x16x32_bf16(a[rt], b, acc[nt][rt], 0, 0, 0);
    }
  }
  __syncthreads();
#pragma unroll
  for (int nt = 0; nt < 2; ++nt) {
    int col = wv * 32 + nt * 16 + l15;
    float bb = bc1[col];
#pragma unroll
    for (int rt = 0; rt < 4; ++rt)
#pragma unroll
      for (int j = 0; j < 4; ++j) {
        int row = rt * 16 + lhi * 4 + j;
        s_lds[row * 256 + (col ^ ((row & 7) << 3))] = f2bu(fmaxf(acc[nt][rt][j] + bb, 0.f));
      }
  }
  __syncthreads();
#pragma unroll
  for (int nt = 0; nt < 2; ++nt)
#pragma unroll
    for (int rt = 0; rt < 4; ++rt) acc[nt][rt] = (f32x4){0.f, 0.f, 0.f, 0.f};
#pragma unroll
  for (int ks = 0; ks < 8; ++ks) {
    bf16x8 a[4];
#pragma unroll
    for (int rt = 0; rt < 4; ++rt)
      a[rt] = lds_frag(s_lds, 256, rt * 16 + l15, ks * 32 + lhi * 8);
#pragma unroll
    for (int nt = 0; nt < 2; ++nt) {
      bf16x8 b = *reinterpret_cast<const bf16x8*>(
          Wc2T + (size_t)(wv * 32 + nt * 16 + l15) * 256 + ks * 32 + lhi * 8);
#pragma unroll
      for (int rt = 0; rt < 4; ++rt)
        acc[nt][rt] = __builtin_amdgcn_mfma_f32_16x16x32_bf16(a[rt], b, acc[nt][rt], 0, 0, 0);
    }
  }
#pragma unroll
  for (int nt = 0; nt < 2; ++nt) {
    int col = wv * 32 + nt * 16 + l15;
    float bb = bc2[col];
#pragma unroll
    for (int rt = 0; rt < 4; ++rt)
#pragma unroll
      for (int j = 0; j < 4; ++j) {
        int row = r0 + rt * 16 + lhi * 4 + j;
        if (row < NB) upd[(size_t)row * 256 + col] = acc[nt][rt][j] + bb;
      }
  }
}

// ---------------- fused LN1 -> FFN(MFMA, quarter-split) -> LN2 ------------
// r10 structure: 512 thr = 8 waves; LDS: h[64][256] 32K + f1q[64][136] 17K.
__global__ __launch_bounds__(512, 4) void ffn_mfma_k(
    const float* __restrict__ feat, const int* __restrict__ seg,
    const float* __restrict__ upd, const unsigned short* __restrict__ Wf1P,
    const float* __restrict__ bf1_, const unsigned short* __restrict__ Wf2P,
    const float* __restrict__ bf2_, const float* __restrict__ lng1,
    const float* __restrict__ lnb1, const float* __restrict__ lng2,
    const float* __restrict__ lnb2, float* __restrict__ out, int N) {
  __shared__ unsigned short h_lds[64 * 256];   // h, later y = h + ffn2
  __shared__ unsigned short f1q_lds[64 * 136]; // f1 quarter, stride 136
  const int t = threadIdx.x;
  const int lane = t & 63;
  const int wv = t >> 6;
  const int l15 = lane & 15;
  const int lhi = lane >> 4;
  const int r0 = blockIdx.x * 64;

  // ---- phase A: h = LN1(feat + upd[seg]) -> bf16 swizzled LDS ----
  {
    float4 g1v = ld4(lng1 + lane * 4);
    float4 b1v = ld4(lnb1 + lane * 4);
    for (int rr = 0; rr < 8; ++rr) {
      int r = wv * 8 + rr;
      int row = r0 + r;
      if (row >= N) row = N - 1;
      int bidx = seg[row];
      float4 xf = ldnt4(feat + (size_t)row * 256 + lane * 4);
      float4 up = ld4(upd + (size_t)bidx * 256 + lane * 4);
      float x0 = xf.x + up.x, x1 = xf.y + up.y;
      float x2 = xf.z + up.z, x3 = xf.w + up.w;
      float s = wsum(x0 + x1 + x2 + x3);
      float s2 = wsum(x0 * x0 + x1 * x1 + x2 * x2 + x3 * x3);
      float mean = s * (1.f / 256.f);
      float var = s2 * (1.f / 256.f) - mean * mean;
      float rstd = rsqrtf(var + 1e-5f);
      ushort4 o;
      o.x = f2bu((x0 - mean) * rstd * g1v.x + b1v.x);
      o.y = f2bu((x1 - mean) * rstd * g1v.y + b1v.y);
      o.z = f2bu((x2 - mean) * rstd * g1v.z + b1v.z);
      o.w = f2bu((x3 - mean) * rstd * g1v.w + b1v.w);
      *reinterpret_cast<ushort4*>(&h_lds[r * 256 + ((lane * 4) ^ ((r & 7) << 3))]) = o;
    }
  }
  __syncthreads();

  f32x4 accC[2][4];
#pragma unroll
  for (int nt = 0; nt < 2; ++nt)
#pragma unroll
    for (int rt = 0; rt < 4; ++rt) accC[nt][rt] = (f32x4){0.f, 0.f, 0.f, 0.f};

#pragma unroll 1
  for (int q = 0; q < 4; ++q) {
    // ---- phase B: f1 quarter (128 cols); wave owns 16 cols ----
    {
      f32x4 accB[4];
#pragma unroll
      for (int rt = 0; rt < 4; ++rt) accB[rt] = (f32x4){0.f, 0.f, 0.f, 0.f};
      // packed weights: block (q, wv, ks); lane-major 1KB, coalesced.
      const unsigned short* wb =
          Wf1P + (size_t)((q * 8 + wv) * 8) * 512 + lane * 8;
      bf16x8 bcur = *reinterpret_cast<const bf16x8*>(wb);
#pragma unroll
      for (int ks = 0; ks < 8; ++ks) {
        bf16x8 bnx = bcur;
        if (ks < 7) bnx = *reinterpret_cast<const bf16x8*>(wb + (ks + 1) * 512);
        int k = ks * 32 + lhi * 8;
        bf16x8 a0 = lds_frag(h_lds, 256, 0 * 16 + l15, k);
        bf16x8 a1 = lds_frag(h_lds, 256, 1 * 16 + l15, k);
        bf16x8 a2 = lds_frag(h_lds, 256, 2 * 16 + l15, k);
        bf16x8 a3 = lds_frag(h_lds, 256, 3 * 16 + l15, k);
        accB[0] = __builtin_amdgcn_mfma_f32_16x16x32_bf16(a0, bcur, accB[0], 0, 0, 0);
        accB[1] = __builtin_amdgcn_mfma_f32_16x16x32_bf16(a1, bcur, accB[1], 0, 0, 0);
        accB[2] = __builtin_amdgcn_mfma_f32_16x16x32_bf16(a2, bcur, accB[2], 0, 0, 0);
        accB[3] = __builtin_amdgcn_mfma_f32_16x16x32_bf16(a3, bcur, accB[3], 0, 0, 0);
        bcur = bnx;
      }
      int coll = wv * 16 + l15;
      float bb = bf1_[q * 128 + coll];
#pragma unroll
      for (int rt = 0; rt < 4; ++rt)
#pragma unroll
        for (int j = 0; j < 4; ++j) {
          int row = rt * 16 + lhi * 4 + j;
          f1q_lds[row * 136 + coll] = f2bu(fmaxf(accB[rt][j] + bb, 0.f));
        }
    }
    __syncthreads();
    // ---- phase C: accC += f1q @ Wf2T[:, q*128:+128] (packed P2) ----
#pragma unroll
    for (int ks = 0; ks < 4; ++ks) {
      int k = ks * 32 + lhi * 8;
      bf16x8 a0 = *reinterpret_cast<const bf16x8*>(f1q_lds + (0 * 16 + l15) * 136 + k);
      bf16x8 a1 = *reinterpret_cast<const bf16x8*>(f1q_lds + (1 * 16 + l15) * 136 + k);
      bf16x8 a2 = *reinterpret_cast<const bf16x8*>(f1q_lds + (2 * 16 + l15) * 136 + k);
      bf16x8 a3 = *reinterpret_cast<const bf16x8*>(f1q_lds + (3 * 16 + l15) * 136 + k);
#pragma unroll
      for (int nt = 0; nt < 2; ++nt) {
        bf16x8 b = *reinterpret_cast<const bf16x8*>(
            Wf2P + (size_t)((wv * 2 + nt) * 16 + q * 4 + ks) * 512 + lane * 8);
        accC[nt][0] = __builtin_amdgcn_mfma_f32_16x16x32_bf16(a0, b, accC[nt][0], 0, 0, 0);
        accC[nt][1] = __builtin_amdgcn_mfma_f32_16x16x32_bf16(a1, b, accC[nt][1], 0, 0, 0);
        accC[nt][2] = __builtin_amdgcn_mfma_f32_16x16x32_bf16(a2, b, accC[nt][2], 0, 0, 0);
        accC[nt][3] = __builtin_amdgcn_mfma_f32_16x16x32_bf16(a3, b, accC[nt][3], 0, 0, 0);
      }
    }
    __syncthreads();
  }

  // ---- y = h + ffn2 + bf2, in place in h_lds ----
#pragma unroll
  for (int nt = 0; nt < 2; ++nt) {
    int c = wv * 32 + nt * 16 + l15;
    float bb = bf2_[c];
#pragma unroll
    for (int rt = 0; rt < 4; ++rt)
#pragma unroll
      for (int j = 0; j < 4; ++j) {
        int row = rt * 16 + lhi * 4 + j;
        int idx = row * 256 + (c ^ ((row & 7) << 3));
        h_lds[idx] = f2bu(us2f(h_lds[idx]) + accC[nt][rt][j] + bb);
      }
  }
  __syncthreads();

  // ---- LN2(y) -> out (plain cached store) ----
  {
    float4 g2v = ld4(lng2 + lane * 4);
    float4 b2v = ld4(lnb2 + lane * 4);
    for (int rr = 0; rr < 8; ++rr) {
      int r = wv * 8 + rr;
      int row = r0 + r;
      if (row >= N) row = N - 1;
      int idx = r * 256 + ((lane * 4) ^ ((r & 7) << 3));
      ushort4 yv = *reinterpret_cast<const ushort4*>(&h_lds[idx]);
      float y0 = us2f(yv.x), y1 = us2f(yv.y), y2 = us2f(yv.z), y3 = us2f(yv.w);
      float s = wsum(y0 + y1 + y2 + y3);
      float s2 = wsum(y0 * y0 + y1 * y1 + y2 * y2 + y3 * y3);
      float mean = s * (1.f / 256.f);
      float var = s2 * (1.f / 256.f) - mean * mean;
      float rstd = rsqrtf(var + 1e-5f);
      float4 o;
      o.x = (y0 - mean) * rstd * g2v.x + b2v.x;
      o.y = (y1 - mean) * rstd * g2v.y + b2v.y;
      o.z = (y2 - mean) * rstd * g2v.z + b2v.z;
      o.w = (y3 - mean) * rstd * g2v.w + b2v.w;
      *reinterpret_cast<float4*>(out + (size_t)row * 256 + lane * 4) = o;
    }
  }
}

extern "C" void kernel_launch(void* const* d_in, const int* in_sizes, int n_in,
                              void* d_out, int out_size, void* d_ws, size_t ws_size,
                              hipStream_t stream) {
  const float* feat = (const float*)d_in[0];
  const float* pos = (const float*)d_in[1];
  const float* bfeat = (const float*)d_in[2];
  const int* seg = (const int*)d_in[3];
  const float* centers = (const float*)d_in[4];
  const float* widths = (const float*)d_in[5];
  const float* Wg = (const float*)d_in[6];
  const float* bg = (const float*)d_in[7];
  const float* Wq = (const float*)d_in[8];
  const float* bq = (const float*)d_in[9];
  const float* Wk = (const float*)d_in[10];
  const float* bk = (const float*)d_in[11];
  const float* Wv = (const float*)d_in[12];
  const float* bv = (const float*)d_in[13];
  const float* Wc1 = (const float*)d_in[14];
  const float* bc1 = (const float*)d_in[15];
  const float* Wc2 = (const float*)d_in[16];
  const float* bc2 = (const float*)d_in[17];
  const float* Wf1 = (const float*)d_in[18];
  const float* bf1_ = (const float*)d_in[19];
  const float* Wf2 = (const float*)d_in[20];
  const float* bf2_ = (const float*)d_in[21];
  const float* lng1 = (const float*)d_in[22];
  const float* lnb1 = (const float*)d_in[23];
  const float* lng2 = (const float*)d_in[24];
  const float* lnb2 = (const float*)d_in[25];
  float* out = (float*)d_out;

  const int N = in_sizes[0] / 256;   // 500000
  const int NB = in_sizes[2] / 256;  // 50000

  size_t off = 0;
  char* wsb = (char*)d_ws;
  auto alloc = [&](size_t bytes) -> void* {
    void* p = wsb + off;
    off += (bytes + 255) & ~(size_t)255;
    return p;
  };
  int* bs = (int*)alloc((size_t)NB * 4);
  int* be = (int*)alloc((size_t)NB * 4);
  float* cent = (float*)alloc((size_t)NB * 3 * 4);
  bf16* geom = (bf16*)alloc((size_t)N * 64 * 2);
  float* u = (float*)alloc((size_t)NB * 320 * 4);
  float* cb = (float*)alloc((size_t)NB * 4);
  float* S = (float*)alloc((size_t)NB * 320 * 4);
  float* upd = (float*)alloc((size_t)NB * 256 * 4);
  unsigned short* WqT = (unsigned short*)alloc((size_t)256 * 256 * 2);
  unsigned short* WkC = (unsigned short*)alloc((size_t)320 * 256 * 2);
  unsigned short* WvT = (unsigned short*)alloc((size_t)256 * 320 * 2);
  unsigned short* Wc1T = (unsigned short*)alloc((size_t)256 * 256 * 2);
  unsigned short* Wc2T = (unsigned short*)alloc((size_t)256 * 256 * 2);
  unsigned short* Wf1P = (unsigned short*)alloc((size_t)512 * 256 * 2);
  unsigned short* Wf2P = (unsigned short*)alloc((size_t)256 * 512 * 2);

  hipMemsetAsync(bs, 0, (size_t)NB * 4, stream);
  hipMemsetAsync(be, 0, (size_t)NB * 4, stream);

  // weight preprocessing (tiny)
  tr_k<<<(256 * 256 + 255) / 256, 256, 0, stream>>>(Wq, WqT, 256, 256);
  cast_k<<<(320 * 256 + 255) / 256, 256, 0, stream>>>(Wk, WkC, 320 * 256);
  tr_k<<<(256 * 320 + 255) / 256, 256, 0, stream>>>(Wv, WvT, 320, 256);
  tr_k<<<(256 * 256 + 255) / 256, 256, 0, stream>>>(Wc1, Wc1T, 256, 256);
  tr_k<<<(256 * 256 + 255) / 256, 256, 0, stream>>>(Wc2, Wc2T, 256, 256);
  pack1_k<<<(512 * 256 + 255) / 256, 256, 0, stream>>>(Wf1, Wf1P);
  pack2_k<<<(512 * 256 + 255) / 256, 256, 0, stream>>>(Wf2, Wf2P);

  bounds_k<<<(N + 255) / 256, 256, 0, stream>>>(seg, bs, be, N);
  cent_k<<<(NB + 255) / 256, 256, 0, stream>>>(pos, bs, be, cent, NB);
  geom_k<<<(N + 255) / 256, 256, 0, stream>>>(pos, seg, cent, centers, widths,
                                              Wg, bg, geom, N);
  const int NBB = (NB + 63) / 64;
  blk1_k<<<NBB, 512, 0, stream>>>(bfeat, WqT, bq, WkC, bk, u, cb, NB);
  attn_k<<<(NB + 3) / 4, 256, 0, stream>>>(feat, geom, u, cb, bs, be, S, NB);
  blk2_k<<<NBB, 512, 0, stream>>>(S, WvT, bv, Wc1T, bc1, Wc2T, bc2, upd, NB);
  ffn_mfma_k<<<(N + 63) / 64, 512, 0, stream>>>(feat, seg, upd, Wf1P, bf1_, Wf2P,
                                                bf2_, lng1, lnb1, lng2, lnb2, out, N);
}